// Round 7
// baseline (625.825 us; speedup 1.0000x reference)
//
#include <hip/hip_runtime.h>
#include <hip/hip_bf16.h>
#include <hip/hip_fp8.h>
#include <stdint.h>

// Problem constants
#define AN 64
#define HN 1024
#define BN 512
#define GAUSS_CONST (-3.989422804014327f)   // V0 / (sqrt(2*pi)*sigma0)
#define INV_2SIG2 2.0f

typedef __attribute__((ext_vector_type(8))) short short8;
typedef __attribute__((ext_vector_type(4))) short short4v;
typedef __attribute__((ext_vector_type(4))) float floatx4;
typedef __attribute__((ext_vector_type(2))) unsigned int uint2v;

__device__ inline unsigned short f2bf(float f) {
  __hip_bfloat16 h = __float2bfloat16(f);        // RNE
  return *reinterpret_cast<unsigned short*>(&h);
}

__device__ inline unsigned char f2fp8(float f) {
  __hip_fp8_e4m3 t(f);                           // OCP e4m3, RNE-sat
  return (unsigned char)t.__x;
}

__device__ inline void gload_lds16(const void* g, void* l) {
  __builtin_amdgcn_global_load_lds(
      (const __attribute__((address_space(1))) void*)g,
      (__attribute__((address_space(3))) void*)l, 16, 0, 0);
}

#define PH_BAR  asm volatile("s_barrier" ::: "memory")
#define WAITV2  asm volatile("s_waitcnt vmcnt(2)" ::: "memory")
#define WAITV0  asm volatile("s_waitcnt vmcnt(0)" ::: "memory")

// ---------------------------------------------------------------------------
// layer 1 forward + pot + gint + inline c_j.  1 block = 1 sample.
__global__ __launch_bounds__(256) void k_fwd1(
    const float* __restrict__ x, const float* __restrict__ W1,
    const float* __restrict__ b1,
    unsigned short* __restrict__ h1bf, float* __restrict__ t1f,
    float* __restrict__ a1, float* __restrict__ potgint) {
  __shared__ float xs[AN];
  __shared__ float red[4];
  int s = blockIdx.x, tid = threadIdx.x;
  if (tid < AN) xs[tid] = x[s * AN + tid];
  __syncthreads();
  #pragma unroll
  for (int cc = 0; cc < 4; ++cc) {
    int j = tid + cc * 256;
    float z = b1[j];
    float cs = 0.f;                      // c_j = sum_a W1[a,j]^2, inline
    #pragma unroll 8
    for (int a = 0; a < AN; ++a) {
      float wv = W1[a * HN + j];
      z += xs[a] * wv;
      cs += wv * wv;
    }
    float h = tanhf(z), t = 1.f - h * h;
    h1bf[s * HN + j] = f2bf(h);
    t1f[s * HN + j] = t;
    a1[s * HN + j] = cs * h * t;
  }
  // pot + gint
  float val = 0.f;
  #pragma unroll
  for (int p = 0; p < 16; ++p) {
    int idx = tid + p * 256;
    int i = idx >> 6, jj = idx & 63;
    if (jj > i) { float d = xs[i] - xs[jj]; val += __expf(-INV_2SIG2 * d * d); }
  }
  val *= GAUSS_CONST;
  if (tid < AN) val += 0.5f * xs[tid] * xs[tid];
  #pragma unroll
  for (int o = 32; o > 0; o >>= 1) val += __shfl_down(val, o, 64);
  if ((tid & 63) == 0) red[tid >> 6] = val;
  __syncthreads();
  if (tid == 0) potgint[s] = red[0] + red[1] + red[2] + red[3];
}

// ---------------------------------------------------------------------------
// packprep (grid-sectioned):
//  b < 256       : P fp8 pack: P8[(s*64+a)][j] = fp8(8 * W1[a,j] * t1[s,j])
//                  tile = 8 samples x 256 j; t1 in regs, W1 L2-reused.
//  256 <= b<512  : W2 64x64 tile -> W2bf (cast) + W2T (bf16 T) + W2T8 (fp8 T, x16)
//  512 <= b<528  : W1 64x64 tile -> W1T (LDS transpose, f32)
__global__ __launch_bounds__(256) void k_packprep(
    const float* __restrict__ W1, const float* __restrict__ t1f,
    const float* __restrict__ W2,
    unsigned char* __restrict__ Pbf8, unsigned short* __restrict__ W2T,
    unsigned short* __restrict__ W2bf, unsigned char* __restrict__ W2T8,
    float* __restrict__ W1T) {
  __shared__ float tile[64][65];
  int b = blockIdx.x, tid = threadIdx.x;
  if (b < 256) {
    int bs = b >> 2, bj = b & 3;
    int s = bs * 8 + (tid >> 5);
    int j0 = bj * 256 + (tid & 31) * 8;
    floatx4 t0  = *reinterpret_cast<const floatx4*>(&t1f[(size_t)s * HN + j0]);
    floatx4 t1v = *reinterpret_cast<const floatx4*>(&t1f[(size_t)s * HN + j0 + 4]);
    size_t outBase = (size_t)s * 64 * HN + j0;
    for (int a = 0; a < AN; ++a) {
      floatx4 w0 = *reinterpret_cast<const floatx4*>(&W1[(size_t)a * HN + j0]);
      floatx4 w1 = *reinterpret_cast<const floatx4*>(&W1[(size_t)a * HN + j0 + 4]);
      unsigned lo = (unsigned)f2fp8(w0[0] * t0[0] * 8.f)
                  | ((unsigned)f2fp8(w0[1] * t0[1] * 8.f) << 8)
                  | ((unsigned)f2fp8(w0[2] * t0[2] * 8.f) << 16)
                  | ((unsigned)f2fp8(w0[3] * t0[3] * 8.f) << 24);
      unsigned hi = (unsigned)f2fp8(w1[0] * t1v[0] * 8.f)
                  | ((unsigned)f2fp8(w1[1] * t1v[1] * 8.f) << 8)
                  | ((unsigned)f2fp8(w1[2] * t1v[2] * 8.f) << 16)
                  | ((unsigned)f2fp8(w1[3] * t1v[3] * 8.f) << 24);
      uint2v o = {lo, hi};
      *reinterpret_cast<uint2v*>(&Pbf8[outBase + (size_t)a * HN]) = o;
    }
  } else if (b < 512) {
    int t = b - 256;
    int jt = (t >> 4) * 64, kt = (t & 15) * 64;
    #pragma unroll
    for (int it = 0; it < 4; ++it) {
      int e = it * 256 + tid;              // vec4 index 0..1023
      int r = e >> 4, cv = (e & 15) * 4;
      floatx4 v = *reinterpret_cast<const floatx4*>(&W2[(size_t)(jt + r) * HN + kt + cv]);
      tile[r][cv] = v[0]; tile[r][cv + 1] = v[1];
      tile[r][cv + 2] = v[2]; tile[r][cv + 3] = v[3];
      short4v o;
      #pragma unroll
      for (int i = 0; i < 4; ++i) o[i] = (short)f2bf(v[i]);
      *reinterpret_cast<short4v*>(&W2bf[(size_t)(jt + r) * HN + kt + cv]) = o;
    }
    __syncthreads();
    #pragma unroll
    for (int it = 0; it < 4; ++it) {
      int e = it * 256 + tid;
      int r = e >> 4, cv = (e & 15) * 4;   // r: k-row in tile, cv: j-cols
      float v0 = tile[cv][r], v1 = tile[cv + 1][r];
      float v2 = tile[cv + 2][r], v3 = tile[cv + 3][r];
      short4v o;
      o[0] = (short)f2bf(v0); o[1] = (short)f2bf(v1);
      o[2] = (short)f2bf(v2); o[3] = (short)f2bf(v3);
      *reinterpret_cast<short4v*>(&W2T[(size_t)(kt + r) * HN + jt + cv]) = o;
      unsigned p8 = (unsigned)f2fp8(v0 * 16.f)
                  | ((unsigned)f2fp8(v1 * 16.f) << 8)
                  | ((unsigned)f2fp8(v2 * 16.f) << 16)
                  | ((unsigned)f2fp8(v3 * 16.f) << 24);
      *reinterpret_cast<unsigned*>(&W2T8[(size_t)(kt + r) * HN + jt + cv]) = p8;
    }
  } else {
    int t = b - 512;                       // 0..15, j-tile of W1 (64 x 1024)
    int j0 = t * 64;
    #pragma unroll
    for (int it = 0; it < 4; ++it) {
      int e = it * 256 + tid;
      int r = e >> 4, cv = (e & 15) * 4;   // r: a-row, cv: j-cols
      floatx4 v = *reinterpret_cast<const floatx4*>(&W1[(size_t)r * HN + j0 + cv]);
      tile[r][cv] = v[0]; tile[r][cv + 1] = v[1];
      tile[r][cv + 2] = v[2]; tile[r][cv + 3] = v[3];
    }
    __syncthreads();
    #pragma unroll
    for (int it = 0; it < 4; ++it) {
      int e = it * 256 + tid;
      int r = e >> 4, cv = (e & 15) * 4;   // r: j-row in tile, cv: a-cols
      floatx4 o;
      #pragma unroll
      for (int i = 0; i < 4; ++i) o[i] = tile[cv + i][r];
      *reinterpret_cast<floatx4*>(&W1T[(size_t)(j0 + r) * AN + cv]) = o;
    }
  }
}

// ---------------------------------------------------------------------------
// z2 = h1 @ W2 + b2 -> dcoef = -2 h2 t2 W3, v = t2*W3 (bf16)
// block tile 16 samples x 64 cols, split-K over 4 waves.
__global__ __launch_bounds__(256) void k_z2(
    const unsigned short* __restrict__ h1bf, const unsigned short* __restrict__ W2T,
    const float* __restrict__ b2, const float* __restrict__ W3,
    float* __restrict__ dcoef, unsigned short* __restrict__ vbf) {
  __shared__ float redL[4 * 16 * 64];
  int n0 = blockIdx.x * 64, m0 = blockIdx.y * 16;
  int tid = threadIdx.x, w = tid >> 6, l = tid & 63, lr = l & 15, kg = l >> 4;
  floatx4 acc[4];
  #pragma unroll
  for (int nf = 0; nf < 4; ++nf) acc[nf] = (floatx4){0.f, 0.f, 0.f, 0.f};
  int arow = m0 + lr;
  for (int kt = 0; kt < 8; ++kt) {
    int kb = w * 256 + kt * 32 + kg * 8;
    short8 af = *reinterpret_cast<const short8*>(&h1bf[arow * HN + kb]);
    #pragma unroll
    for (int nf = 0; nf < 4; ++nf) {
      short8 bf_ = *reinterpret_cast<const short8*>(&W2T[(n0 + nf * 16 + lr) * HN + kb]);
      acc[nf] = __builtin_amdgcn_mfma_f32_16x16x32_bf16(af, bf_, acc[nf], 0, 0, 0);
    }
  }
  #pragma unroll
  for (int nf = 0; nf < 4; ++nf)
    #pragma unroll
    for (int r = 0; r < 4; ++r)
      redL[w * 1024 + (kg * 4 + r) * 64 + nf * 16 + lr] = acc[nf][r];
  __syncthreads();
  #pragma unroll
  for (int t = 0; t < 4; ++t) {
    int e = tid + t * 256;
    float z = redL[e] + redL[1024 + e] + redL[2048 + e] + redL[3072 + e];
    int row = e >> 6, col = e & 63;
    int s = m0 + row, k2 = n0 + col;
    z += b2[k2];
    float h = tanhf(z), tt = 1.f - h * h, w3 = W3[k2];
    dcoef[s * HN + k2] = -2.f * h * tt * w3;
    vbf[s * HN + k2] = f2bf(tt * w3);
  }
}

// ---------------------------------------------------------------------------
// w = v @ W2^T  (w[s,j] = sum_k v[s,k] W2[j,k]) -> store f32
__global__ __launch_bounds__(256) void k_w(
    const unsigned short* __restrict__ vbf, const unsigned short* __restrict__ W2bf,
    float* __restrict__ wbuf) {
  __shared__ float redL[4 * 16 * 64];
  int n0 = blockIdx.x * 64, m0 = blockIdx.y * 16;
  int tid = threadIdx.x, w = tid >> 6, l = tid & 63, lr = l & 15, kg = l >> 4;
  floatx4 acc[4];
  #pragma unroll
  for (int nf = 0; nf < 4; ++nf) acc[nf] = (floatx4){0.f, 0.f, 0.f, 0.f};
  int arow = m0 + lr;
  for (int kt = 0; kt < 8; ++kt) {
    int kb = w * 256 + kt * 32 + kg * 8;
    short8 af = *reinterpret_cast<const short8*>(&vbf[arow * HN + kb]);
    #pragma unroll
    for (int nf = 0; nf < 4; ++nf) {
      short8 bf_ = *reinterpret_cast<const short8*>(&W2bf[(n0 + nf * 16 + lr) * HN + kb]);
      acc[nf] = __builtin_amdgcn_mfma_f32_16x16x32_bf16(af, bf_, acc[nf], 0, 0, 0);
    }
  }
  #pragma unroll
  for (int nf = 0; nf < 4; ++nf)
    #pragma unroll
    for (int r = 0; r < 4; ++r)
      redL[w * 1024 + (kg * 4 + r) * 64 + nf * 16 + lr] = acc[nf][r];
  __syncthreads();
  #pragma unroll
  for (int t = 0; t < 4; ++t) {
    int e = tid + t * 256;
    float z = redL[e] + redL[1024 + e] + redL[2048 + e] + redL[3072 + e];
    int row = e >> 6, col = e & 63;
    wbuf[(m0 + row) * HN + (n0 + col)] = z;
  }
}

// ---------------------------------------------------------------------------
// BIG fp8 (e4m3, P x8 / W2 x16, epilogue /16384), 8-phase T3+T4+T5.
// q[s,k] = sum_a M[a,k]^2, M = P[s] @ W2.  BM=256 (4 samples) x BN=256,
// BK=64 (2 k-halves of 32 fp8 = 32 B rows). 512 threads = 8 waves (2M x 4N).
// LDS: 2 dbuf x 2 khalf x (256x32 B) x {A,B} = 64 KB -> 2 blocks/CU.
// Linear LDS, NO swizzle: 32 B row stride makes ds_read_b64 frag reads
// uniformly distributed (4 lanes/bank-pair = wave64 minimum). Staging is
// 1 gload_lds16/thread/half; counted vmcnt(2) at phases 1,3.
// XCD map: xcd=flat&7 owns py range xcd*16..+16, px=local&3 fastest ->
// the 4 blocks sharing an A-panel are co-dispatched on ONE XCD (A fetched
// once chip-wide); full fp8 W2T (1 MB) L2-resident per XCD.
__global__ __launch_bounds__(512, 4) void k_big8(
    const unsigned char* __restrict__ Pbf8,   // [32768][HN] fp8
    const unsigned char* __restrict__ W2T8,   // [1024][1024] fp8
    float* __restrict__ q) {
  extern __shared__ unsigned char sm8[];      // A: 4x8192 @0, B: 4x8192 @32768

  int flat = blockIdx.x;
  int xcd = flat & 7, local = flat >> 3;      // consecutive blocks round-robin XCDs
  int px = local & 3;                          // col panel (fastest)
  int py = xcd * 16 + (local >> 2);            // 0..127, XCD-exclusive A range

  int tid = threadIdx.x;
  int wid = tid >> 6, l = tid & 63;
  int lr = l & 15, kg = l >> 4;
  int wr = wid >> 2, wc = wid & 3;             // wave grid 2M x 4N
  int wr128 = wr * 128, wc64 = wc * 64;

  // staging: thread covers row tid>>1, 16B at (tid&1)*16 (linear, tid*16)
  int srow = tid >> 1, soff = (tid & 1) * 16;
  const unsigned char* aSrc = &Pbf8[(size_t)(py * 256 + srow) * HN + soff];
  const unsigned char* bSrc = &W2T8[(size_t)(px * 256 + srow) * HN + soff];

  auto stA = [&](int buf, int tt, int kh) {
    gload_lds16(aSrc + tt * 64 + kh * 32, &sm8[(buf * 2 + kh) * 8192 + tid * 16]);
  };
  auto stB = [&](int buf, int tt, int kh) {
    gload_lds16(bSrc + tt * 64 + kh * 32, &sm8[32768 + (buf * 2 + kh) * 8192 + tid * 16]);
  };

  floatx4 acc[8][4];
  #pragma unroll
  for (int m = 0; m < 8; ++m)
    #pragma unroll
    for (int n = 0; n < 4; ++n) acc[m][n] = (floatx4){0.f, 0.f, 0.f, 0.f};

  long af[8], bfr[2];
  auto ldA = [&](int buf, int kh) {
    const unsigned char* Ap = &sm8[(buf * 2 + kh) * 8192];
    #pragma unroll
    for (int m = 0; m < 8; ++m)
      af[m] = *reinterpret_cast<const long*>(&Ap[(wr128 + m * 16 + lr) * 32 + kg * 8]);
  };
  auto ldB = [&](int buf, int kh, int nh) {
    const unsigned char* Bp = &sm8[32768 + (buf * 2 + kh) * 8192];
    #pragma unroll
    for (int n = 0; n < 2; ++n)
      bfr[n] = *reinterpret_cast<const long*>(&Bp[(wc64 + (nh * 2 + n) * 16 + lr) * 32 + kg * 8]);
  };
  auto mm = [&](int nh) {
    __builtin_amdgcn_s_setprio(1);
    #pragma unroll
    for (int m = 0; m < 8; ++m)
      #pragma unroll
      for (int n = 0; n < 2; ++n)
        acc[m][nh * 2 + n] = __builtin_amdgcn_mfma_f32_16x16x32_fp8_fp8(
            af[m], bfr[n], acc[m][nh * 2 + n], 0, 0, 0);
    __builtin_amdgcn_s_setprio(0);
  };

  // prologue: stage 4 halves of tile 0 (4 loads); wait until k0 A,B done
  stA(0, 0, 0); stB(0, 0, 0); stA(0, 0, 1); stB(0, 0, 1);
  WAITV2; PH_BAR;

  for (int t = 0; t < 16; ++t) {
    int buf = t & 1, nb = buf ^ 1;
    bool more = (t < 15);
    // ph0: (k0, nh0)
    ldA(buf, 0); ldB(buf, 0, 0);
    if (more) stA(nb, t + 1, 0);
    PH_BAR; mm(0); PH_BAR;
    // ph1: (k0, nh1); guard k1 halves
    ldB(buf, 0, 1);
    if (more) { stB(nb, t + 1, 0); WAITV2; } else { WAITV0; }
    PH_BAR; mm(1); PH_BAR;
    // ph2: (k1, nh0)
    ldA(buf, 1); ldB(buf, 1, 0);
    if (more) stA(nb, t + 1, 1);
    PH_BAR; mm(0); PH_BAR;
    // ph3: (k1, nh1); guard next tile's k0 halves
    ldB(buf, 1, 1);
    if (more) { stB(nb, t + 1, 1); WAITV2; }
    PH_BAR; mm(1); PH_BAR;
  }

  // epilogue: per wave 2 samples x 64 cols; reduce rows of M'^2 / 16384
  int colBase = px * 256 + wc64;
  #pragma unroll
  for (int half = 0; half < 2; ++half) {
    int sOut = py * 4 + wr * 2 + half;
    #pragma unroll
    for (int nf = 0; nf < 4; ++nf) {
      float v = 0.f;
      #pragma unroll
      for (int mf = half * 4; mf < half * 4 + 4; ++mf)
        #pragma unroll
        for (int r = 0; r < 4; ++r) v += acc[mf][nf][r] * acc[mf][nf][r];
      v += __shfl_xor(v, 16, 64);
      v += __shfl_xor(v, 32, 64);
      v *= (1.f / 16384.f);                 // undo (8x)*(16x) operand scaling
      if (l < 16) q[(size_t)sOut * HN + colBase + nf * 16 + l] = v;
    }
  }
}

// ---------------------------------------------------------------------------
// finale: per sample combine T1, T2, sum g^2, pot+gint
__global__ __launch_bounds__(256) void k_fin(
    const float* __restrict__ wbuf, const float* __restrict__ a1,
    const float* __restrict__ dcoef, const float* __restrict__ q,
    const float* __restrict__ t1f, const float* __restrict__ W1T,
    const float* __restrict__ potgint, float* __restrict__ out) {
  __shared__ float s_lds[HN];
  __shared__ float gl[256];
  __shared__ float red1[4], red2[4];
  int s = blockIdx.x, tid = threadIdx.x;
  float p1 = 0.f, p2 = 0.f;
  #pragma unroll
  for (int cc = 0; cc < 4; ++cc) {
    int j = tid + cc * 256;
    float wv = wbuf[s * HN + j];
    p1 += a1[s * HN + j] * wv;
    p2 += dcoef[s * HN + j] * q[s * HN + j];
    s_lds[j] = t1f[s * HN + j] * wv;
  }
  __syncthreads();
  int part = tid >> 6, a = tid & 63;
  float gp = 0.f;
  for (int jj = part * 256; jj < part * 256 + 256; ++jj)
    gp += s_lds[jj] * W1T[jj * AN + a];
  gl[tid] = gp;
  #pragma unroll
  for (int o = 32; o > 0; o >>= 1) { p1 += __shfl_down(p1, o, 64); p2 += __shfl_down(p2, o, 64); }
  if ((tid & 63) == 0) { red1[tid >> 6] = p1; red2[tid >> 6] = p2; }
  __syncthreads();
  if (tid < 64) {
    float g = gl[tid] + gl[64 + tid] + gl[128 + tid] + gl[192 + tid];
    float sq = g * g;
    #pragma unroll
    for (int o = 32; o > 0; o >>= 1) sq += __shfl_down(sq, o, 64);
    if (tid == 0) {
      float T1 = -2.f * (red1[0] + red1[1] + red1[2] + red1[3]);
      float T2 = red2[0] + red2[1] + red2[2] + red2[3];
      out[s] = -0.5f * (T1 + T2 + sq) + potgint[s];
    }
  }
}

// ---------------------------------------------------------------------------
extern "C" void kernel_launch(void* const* d_in, const int* in_sizes, int n_in,
                              void* d_out, int out_size, void* d_ws, size_t ws_size,
                              hipStream_t stream) {
  const float* x  = (const float*)d_in[0];
  const float* W1 = (const float*)d_in[1];
  const float* b1 = (const float*)d_in[2];
  const float* W2 = (const float*)d_in[3];
  const float* b2 = (const float*)d_in[4];
  const float* W3 = (const float*)d_in[5];
  float* out = (float*)d_out;

  char* ws = (char*)d_ws;
  size_t off = 0;
  auto alloc = [&](size_t bytes) -> void* {
    void* p = ws + off; off += (bytes + 255) & ~(size_t)255; return p;
  };
  unsigned short* W2T  = (unsigned short*)alloc((size_t)HN * HN * 2);
  unsigned short* W2bf = (unsigned short*)alloc((size_t)HN * HN * 2);
  unsigned char*  W2T8 = (unsigned char*)alloc((size_t)HN * HN);
  float*          W1T  = (float*)alloc((size_t)AN * HN * 4);
  unsigned short* h1bf = (unsigned short*)alloc((size_t)BN * HN * 2);
  float*          t1f  = (float*)alloc((size_t)BN * HN * 4);
  float*          a1   = (float*)alloc((size_t)BN * HN * 4);
  float*          dcoef= (float*)alloc((size_t)BN * HN * 4);
  unsigned short* vbf  = (unsigned short*)alloc((size_t)BN * HN * 2);
  float*          wbuf = (float*)alloc((size_t)BN * HN * 4);
  float*          q    = (float*)alloc((size_t)BN * HN * 4);
  float*          pg   = (float*)alloc((size_t)BN * 4);
  // full-batch fp8 P buffer: 512 samples x 64 x 1024 = 33.5 MB
  unsigned char*  Pbf8 = (unsigned char*)alloc((size_t)BN * AN * HN);

  static bool attrSet = false;
  if (!attrSet) {
    hipFuncSetAttribute((const void*)k_big8,
                        hipFuncAttributeMaxDynamicSharedMemorySize, 65536);
    attrSet = true;
  }

  k_fwd1<<<dim3(BN), 256, 0, stream>>>(x, W1, b1, h1bf, t1f, a1, pg);
  k_packprep<<<dim3(256 + 256 + 16), 256, 0, stream>>>(W1, t1f, W2,
                                                       Pbf8, W2T, W2bf, W2T8, W1T);
  k_z2<<<dim3(HN / 64, BN / 16), 256, 0, stream>>>(h1bf, W2T, b2, W3, dcoef, vbf);
  k_w<<<dim3(HN / 64, BN / 16), 256, 0, stream>>>(vbf, W2bf, wbuf);
  k_big8<<<dim3(512), 512, 65536, stream>>>(Pbf8, W2T8, q);
  k_fin<<<dim3(BN), 256, 0, stream>>>(wbuf, a1, dcoef, q, t1f, W1T, pg, out);
}

// Round 8
// 195.868 us; speedup vs baseline: 3.1951x; 3.1951x over previous
//
#include <hip/hip_runtime.h>
#include <hip/hip_bf16.h>
#include <hip/hip_fp8.h>
#include <stdint.h>

// Problem constants
#define AN 64
#define HN 1024
#define BN 512
#define GAUSS_CONST (-3.989422804014327f)   // V0 / (sqrt(2*pi)*sigma0)
#define INV_2SIG2 2.0f

typedef __attribute__((ext_vector_type(8))) short short8;
typedef __attribute__((ext_vector_type(4))) short short4v;
typedef __attribute__((ext_vector_type(4))) float floatx4;
typedef __attribute__((ext_vector_type(2))) unsigned int uint2v;

__device__ inline unsigned short f2bf(float f) {
  __hip_bfloat16 h = __float2bfloat16(f);        // RNE
  return *reinterpret_cast<unsigned short*>(&h);
}

__device__ inline unsigned char f2fp8(float f) {
  __hip_fp8_e4m3 t(f);                           // OCP e4m3, RNE-sat
  return (unsigned char)t.__x;
}

__device__ inline void gload_lds16(const void* g, void* l) {
  __builtin_amdgcn_global_load_lds(
      (const __attribute__((address_space(1))) void*)g,
      (__attribute__((address_space(3))) void*)l, 16, 0, 0);
}

#define PH_BAR  asm volatile("s_barrier" ::: "memory")
#define WAITV2  asm volatile("s_waitcnt vmcnt(2)" ::: "memory")
#define WAITV0  asm volatile("s_waitcnt vmcnt(0)" ::: "memory")

// ---------------------------------------------------------------------------
// layer 1 forward + pot + gint + inline c_j.  1 block = 1 sample.
__global__ __launch_bounds__(256) void k_fwd1(
    const float* __restrict__ x, const float* __restrict__ W1,
    const float* __restrict__ b1,
    unsigned short* __restrict__ h1bf, float* __restrict__ t1f,
    float* __restrict__ a1, float* __restrict__ potgint) {
  __shared__ float xs[AN];
  __shared__ float red[4];
  int s = blockIdx.x, tid = threadIdx.x;
  if (tid < AN) xs[tid] = x[s * AN + tid];
  __syncthreads();
  #pragma unroll
  for (int cc = 0; cc < 4; ++cc) {
    int j = tid + cc * 256;
    float z = b1[j];
    float cs = 0.f;                      // c_j = sum_a W1[a,j]^2, inline
    #pragma unroll 8
    for (int a = 0; a < AN; ++a) {
      float wv = W1[a * HN + j];
      z += xs[a] * wv;
      cs += wv * wv;
    }
    float h = tanhf(z), t = 1.f - h * h;
    h1bf[s * HN + j] = f2bf(h);
    t1f[s * HN + j] = t;
    a1[s * HN + j] = cs * h * t;
  }
  // pot + gint
  float val = 0.f;
  #pragma unroll
  for (int p = 0; p < 16; ++p) {
    int idx = tid + p * 256;
    int i = idx >> 6, jj = idx & 63;
    if (jj > i) { float d = xs[i] - xs[jj]; val += __expf(-INV_2SIG2 * d * d); }
  }
  val *= GAUSS_CONST;
  if (tid < AN) val += 0.5f * xs[tid] * xs[tid];
  #pragma unroll
  for (int o = 32; o > 0; o >>= 1) val += __shfl_down(val, o, 64);
  if ((tid & 63) == 0) red[tid >> 6] = val;
  __syncthreads();
  if (tid == 0) potgint[s] = red[0] + red[1] + red[2] + red[3];
}

// ---------------------------------------------------------------------------
// packprep (grid-sectioned):
//  b < 256       : P fp8 pack: P8[(s*64+a)][j] = fp8(8 * W1[a,j] * t1[s,j])
//  256 <= b<512  : W2 64x64 tile -> W2bf (cast) + W2T (bf16 T) + W2T8 (fp8 T, x16)
//  512 <= b<528  : W1 64x64 tile -> W1T (LDS transpose, f32)
__global__ __launch_bounds__(256) void k_packprep(
    const float* __restrict__ W1, const float* __restrict__ t1f,
    const float* __restrict__ W2,
    unsigned char* __restrict__ Pbf8, unsigned short* __restrict__ W2T,
    unsigned short* __restrict__ W2bf, unsigned char* __restrict__ W2T8,
    float* __restrict__ W1T) {
  __shared__ float tile[64][65];
  int b = blockIdx.x, tid = threadIdx.x;
  if (b < 256) {
    int bs = b >> 2, bj = b & 3;
    int s = bs * 8 + (tid >> 5);
    int j0 = bj * 256 + (tid & 31) * 8;
    floatx4 t0  = *reinterpret_cast<const floatx4*>(&t1f[(size_t)s * HN + j0]);
    floatx4 t1v = *reinterpret_cast<const floatx4*>(&t1f[(size_t)s * HN + j0 + 4]);
    size_t outBase = (size_t)s * 64 * HN + j0;
    for (int a = 0; a < AN; ++a) {
      floatx4 w0 = *reinterpret_cast<const floatx4*>(&W1[(size_t)a * HN + j0]);
      floatx4 w1 = *reinterpret_cast<const floatx4*>(&W1[(size_t)a * HN + j0 + 4]);
      unsigned lo = (unsigned)f2fp8(w0[0] * t0[0] * 8.f)
                  | ((unsigned)f2fp8(w0[1] * t0[1] * 8.f) << 8)
                  | ((unsigned)f2fp8(w0[2] * t0[2] * 8.f) << 16)
                  | ((unsigned)f2fp8(w0[3] * t0[3] * 8.f) << 24);
      unsigned hi = (unsigned)f2fp8(w1[0] * t1v[0] * 8.f)
                  | ((unsigned)f2fp8(w1[1] * t1v[1] * 8.f) << 8)
                  | ((unsigned)f2fp8(w1[2] * t1v[2] * 8.f) << 16)
                  | ((unsigned)f2fp8(w1[3] * t1v[3] * 8.f) << 24);
      uint2v o = {lo, hi};
      *reinterpret_cast<uint2v*>(&Pbf8[outBase + (size_t)a * HN]) = o;
    }
  } else if (b < 512) {
    int t = b - 256;
    int jt = (t >> 4) * 64, kt = (t & 15) * 64;
    #pragma unroll
    for (int it = 0; it < 4; ++it) {
      int e = it * 256 + tid;              // vec4 index 0..1023
      int r = e >> 4, cv = (e & 15) * 4;
      floatx4 v = *reinterpret_cast<const floatx4*>(&W2[(size_t)(jt + r) * HN + kt + cv]);
      tile[r][cv] = v[0]; tile[r][cv + 1] = v[1];
      tile[r][cv + 2] = v[2]; tile[r][cv + 3] = v[3];
      short4v o;
      #pragma unroll
      for (int i = 0; i < 4; ++i) o[i] = (short)f2bf(v[i]);
      *reinterpret_cast<short4v*>(&W2bf[(size_t)(jt + r) * HN + kt + cv]) = o;
    }
    __syncthreads();
    #pragma unroll
    for (int it = 0; it < 4; ++it) {
      int e = it * 256 + tid;
      int r = e >> 4, cv = (e & 15) * 4;   // r: k-row in tile, cv: j-cols
      float v0 = tile[cv][r], v1 = tile[cv + 1][r];
      float v2 = tile[cv + 2][r], v3 = tile[cv + 3][r];
      short4v o;
      o[0] = (short)f2bf(v0); o[1] = (short)f2bf(v1);
      o[2] = (short)f2bf(v2); o[3] = (short)f2bf(v3);
      *reinterpret_cast<short4v*>(&W2T[(size_t)(kt + r) * HN + jt + cv]) = o;
      unsigned p8 = (unsigned)f2fp8(v0 * 16.f)
                  | ((unsigned)f2fp8(v1 * 16.f) << 8)
                  | ((unsigned)f2fp8(v2 * 16.f) << 16)
                  | ((unsigned)f2fp8(v3 * 16.f) << 24);
      *reinterpret_cast<unsigned*>(&W2T8[(size_t)(kt + r) * HN + jt + cv]) = p8;
    }
  } else {
    int t = b - 512;                       // 0..15, j-tile of W1 (64 x 1024)
    int j0 = t * 64;
    #pragma unroll
    for (int it = 0; it < 4; ++it) {
      int e = it * 256 + tid;
      int r = e >> 4, cv = (e & 15) * 4;   // r: a-row, cv: j-cols
      floatx4 v = *reinterpret_cast<const floatx4*>(&W1[(size_t)r * HN + j0 + cv]);
      tile[r][cv] = v[0]; tile[r][cv + 1] = v[1];
      tile[r][cv + 2] = v[2]; tile[r][cv + 3] = v[3];
    }
    __syncthreads();
    #pragma unroll
    for (int it = 0; it < 4; ++it) {
      int e = it * 256 + tid;
      int r = e >> 4, cv = (e & 15) * 4;   // r: j-row in tile, cv: a-cols
      floatx4 o;
      #pragma unroll
      for (int i = 0; i < 4; ++i) o[i] = tile[cv + i][r];
      *reinterpret_cast<floatx4*>(&W1T[(size_t)(j0 + r) * AN + cv]) = o;
    }
  }
}

// ---------------------------------------------------------------------------
// z2 = h1 @ W2 + b2 -> dcoef = -2 h2 t2 W3, v = t2*W3 (bf16)
// block tile 16 samples x 64 cols, split-K over 4 waves.
__global__ __launch_bounds__(256) void k_z2(
    const unsigned short* __restrict__ h1bf, const unsigned short* __restrict__ W2T,
    const float* __restrict__ b2, const float* __restrict__ W3,
    float* __restrict__ dcoef, unsigned short* __restrict__ vbf) {
  __shared__ float redL[4 * 16 * 64];
  int n0 = blockIdx.x * 64, m0 = blockIdx.y * 16;
  int tid = threadIdx.x, w = tid >> 6, l = tid & 63, lr = l & 15, kg = l >> 4;
  floatx4 acc[4];
  #pragma unroll
  for (int nf = 0; nf < 4; ++nf) acc[nf] = (floatx4){0.f, 0.f, 0.f, 0.f};
  int arow = m0 + lr;
  for (int kt = 0; kt < 8; ++kt) {
    int kb = w * 256 + kt * 32 + kg * 8;
    short8 af = *reinterpret_cast<const short8*>(&h1bf[arow * HN + kb]);
    #pragma unroll
    for (int nf = 0; nf < 4; ++nf) {
      short8 bf_ = *reinterpret_cast<const short8*>(&W2T[(n0 + nf * 16 + lr) * HN + kb]);
      acc[nf] = __builtin_amdgcn_mfma_f32_16x16x32_bf16(af, bf_, acc[nf], 0, 0, 0);
    }
  }
  #pragma unroll
  for (int nf = 0; nf < 4; ++nf)
    #pragma unroll
    for (int r = 0; r < 4; ++r)
      redL[w * 1024 + (kg * 4 + r) * 64 + nf * 16 + lr] = acc[nf][r];
  __syncthreads();
  #pragma unroll
  for (int t = 0; t < 4; ++t) {
    int e = tid + t * 256;
    float z = redL[e] + redL[1024 + e] + redL[2048 + e] + redL[3072 + e];
    int row = e >> 6, col = e & 63;
    int s = m0 + row, k2 = n0 + col;
    z += b2[k2];
    float h = tanhf(z), tt = 1.f - h * h, w3 = W3[k2];
    dcoef[s * HN + k2] = -2.f * h * tt * w3;
    vbf[s * HN + k2] = f2bf(tt * w3);
  }
}

// ---------------------------------------------------------------------------
// w = v @ W2^T  (w[s,j] = sum_k v[s,k] W2[j,k]) -> store f32
__global__ __launch_bounds__(256) void k_w(
    const unsigned short* __restrict__ vbf, const unsigned short* __restrict__ W2bf,
    float* __restrict__ wbuf) {
  __shared__ float redL[4 * 16 * 64];
  int n0 = blockIdx.x * 64, m0 = blockIdx.y * 16;
  int tid = threadIdx.x, w = tid >> 6, l = tid & 63, lr = l & 15, kg = l >> 4;
  floatx4 acc[4];
  #pragma unroll
  for (int nf = 0; nf < 4; ++nf) acc[nf] = (floatx4){0.f, 0.f, 0.f, 0.f};
  int arow = m0 + lr;
  for (int kt = 0; kt < 8; ++kt) {
    int kb = w * 256 + kt * 32 + kg * 8;
    short8 af = *reinterpret_cast<const short8*>(&vbf[arow * HN + kb]);
    #pragma unroll
    for (int nf = 0; nf < 4; ++nf) {
      short8 bf_ = *reinterpret_cast<const short8*>(&W2bf[(n0 + nf * 16 + lr) * HN + kb]);
      acc[nf] = __builtin_amdgcn_mfma_f32_16x16x32_bf16(af, bf_, acc[nf], 0, 0, 0);
    }
  }
  #pragma unroll
  for (int nf = 0; nf < 4; ++nf)
    #pragma unroll
    for (int r = 0; r < 4; ++r)
      redL[w * 1024 + (kg * 4 + r) * 64 + nf * 16 + lr] = acc[nf][r];
  __syncthreads();
  #pragma unroll
  for (int t = 0; t < 4; ++t) {
    int e = tid + t * 256;
    float z = redL[e] + redL[1024 + e] + redL[2048 + e] + redL[3072 + e];
    int row = e >> 6, col = e & 63;
    wbuf[(m0 + row) * HN + (n0 + col)] = z;
  }
}

// ---------------------------------------------------------------------------
// BIG fp8 (e4m3, P x8 / W2 x16, epilogue /16384), 8-phase T3+T4+T5.
// q[s,k] = sum_a M[a,k]^2, M = P[s] @ W2.  BM=256 (4 samples) x BN=256,
// BK=64 (2 k-halves of 32 fp8 = 32 B rows). 512 threads = 8 waves (2M x 4N).
// LDS: 2 dbuf x 2 khalf x (256x32 B) x {A,B} = 64 KB.
// __launch_bounds__(512,2): cap 256 regs/wave -- acc[8][4]=128 AGPR + ~40
// arch VGPR must NOT spill (R7's (512,4) capped combined at 128 -> scratch
// catastrophe: 1.2GB writes, 7x slowdown).
// LDS swizzle (16B granularity, 2-way residual = free): read slot
// kg ^ (((lr>>2)&1)<<1); staging source chunk pre-swizzled by the same
// involution (chunk ^ ((row>>2)&1)) so gload_lds dest stays linear.
// XCD map: xcd=flat&7 owns py range xcd*16..+16, px=local&3 fastest ->
// 4 blocks sharing an A-panel co-resident on ONE XCD; W2T8 (1MB) L2-res.
__global__ __launch_bounds__(512, 2) void k_big8(
    const unsigned char* __restrict__ Pbf8,   // [32768][HN] fp8
    const unsigned char* __restrict__ W2T8,   // [1024][1024] fp8
    float* __restrict__ q) {
  extern __shared__ unsigned char sm8[];      // A: 4x8192 @0, B: 4x8192 @32768

  int flat = blockIdx.x;
  int xcd = flat & 7, local = flat >> 3;      // consecutive blocks round-robin XCDs
  int px = local & 3;                          // col panel (fastest)
  int py = xcd * 16 + (local >> 2);            // 0..127, XCD-exclusive A range

  int tid = threadIdx.x;
  int wid = tid >> 6, l = tid & 63;
  int lr = l & 15, kg = l >> 4;
  int wr = wid >> 2, wc = wid & 3;             // wave grid 2M x 4N
  int wr128 = wr * 128, wc64 = wc * 64;
  // read-side swizzled 8B slot: rows repeat banks every 4; XOR 16B chunk
  // with (row>>2)&1.  (row>>2)&1 == (lr>>2)&1 for all frag rows (m*16, wc64
  // etc. have bit2 == 0), so it's a per-thread constant.
  int sl8 = ((kg ^ (((lr >> 2) & 1) << 1)) * 8);

  // staging: thread covers row tid>>1, phys 16B chunk tid&1 (dest linear
  // tid*16); global source chunk = (tid&1) ^ ((row>>2)&1) = (tid&1)^((tid>>3)&1)
  int srow = tid >> 1;
  int soff = (((tid & 1) ^ ((tid >> 3) & 1)) << 4);
  const unsigned char* aSrc = &Pbf8[(size_t)(py * 256 + srow) * HN + soff];
  const unsigned char* bSrc = &W2T8[(size_t)(px * 256 + srow) * HN + soff];

  auto stA = [&](int buf, int tt, int kh) {
    gload_lds16(aSrc + tt * 64 + kh * 32, &sm8[(buf * 2 + kh) * 8192 + tid * 16]);
  };
  auto stB = [&](int buf, int tt, int kh) {
    gload_lds16(bSrc + tt * 64 + kh * 32, &sm8[32768 + (buf * 2 + kh) * 8192 + tid * 16]);
  };

  floatx4 acc[8][4];
  #pragma unroll
  for (int m = 0; m < 8; ++m)
    #pragma unroll
    for (int n = 0; n < 4; ++n) acc[m][n] = (floatx4){0.f, 0.f, 0.f, 0.f};

  long af[8], bfr[2];
  auto ldA = [&](int buf, int kh) {
    const unsigned char* Ap = &sm8[(buf * 2 + kh) * 8192];
    #pragma unroll
    for (int m = 0; m < 8; ++m)
      af[m] = *reinterpret_cast<const long*>(&Ap[(wr128 + m * 16 + lr) * 32 + sl8]);
  };
  auto ldB = [&](int buf, int kh, int nh) {
    const unsigned char* Bp = &sm8[32768 + (buf * 2 + kh) * 8192];
    #pragma unroll
    for (int n = 0; n < 2; ++n)
      bfr[n] = *reinterpret_cast<const long*>(&Bp[(wc64 + (nh * 2 + n) * 16 + lr) * 32 + sl8]);
  };
  auto mm = [&](int nh) {
    __builtin_amdgcn_s_setprio(1);
    #pragma unroll
    for (int m = 0; m < 8; ++m)
      #pragma unroll
      for (int n = 0; n < 2; ++n)
        acc[m][nh * 2 + n] = __builtin_amdgcn_mfma_f32_16x16x32_fp8_fp8(
            af[m], bfr[n], acc[m][nh * 2 + n], 0, 0, 0);
    __builtin_amdgcn_s_setprio(0);
  };

  // prologue: stage 4 halves of tile 0 (4 loads); wait until k0 A,B done
  stA(0, 0, 0); stB(0, 0, 0); stA(0, 0, 1); stB(0, 0, 1);
  WAITV2; PH_BAR;

  for (int t = 0; t < 16; ++t) {
    int buf = t & 1, nb = buf ^ 1;
    bool more = (t < 15);
    // ph0: (k0, nh0)
    ldA(buf, 0); ldB(buf, 0, 0);
    if (more) stA(nb, t + 1, 0);
    PH_BAR; mm(0); PH_BAR;
    // ph1: (k0, nh1); guard k1 halves
    ldB(buf, 0, 1);
    if (more) { stB(nb, t + 1, 0); WAITV2; } else { WAITV0; }
    PH_BAR; mm(1); PH_BAR;
    // ph2: (k1, nh0)
    ldA(buf, 1); ldB(buf, 1, 0);
    if (more) stA(nb, t + 1, 1);
    PH_BAR; mm(0); PH_BAR;
    // ph3: (k1, nh1); guard next tile's k0 halves
    ldB(buf, 1, 1);
    if (more) { stB(nb, t + 1, 1); WAITV2; }
    PH_BAR; mm(1); PH_BAR;
  }

  // epilogue: per wave 2 samples x 64 cols; reduce rows of M'^2 / 16384
  int colBase = px * 256 + wc64;
  #pragma unroll
  for (int half = 0; half < 2; ++half) {
    int sOut = py * 4 + wr * 2 + half;
    #pragma unroll
    for (int nf = 0; nf < 4; ++nf) {
      float v = 0.f;
      #pragma unroll
      for (int mf = half * 4; mf < half * 4 + 4; ++mf)
        #pragma unroll
        for (int r = 0; r < 4; ++r) v += acc[mf][nf][r] * acc[mf][nf][r];
      v += __shfl_xor(v, 16, 64);
      v += __shfl_xor(v, 32, 64);
      v *= (1.f / 16384.f);                 // undo (8x)*(16x) operand scaling
      if (l < 16) q[(size_t)sOut * HN + colBase + nf * 16 + l] = v;
    }
  }
}

// ---------------------------------------------------------------------------
// finale: per sample combine T1, T2, sum g^2, pot+gint
__global__ __launch_bounds__(256) void k_fin(
    const float* __restrict__ wbuf, const float* __restrict__ a1,
    const float* __restrict__ dcoef, const float* __restrict__ q,
    const float* __restrict__ t1f, const float* __restrict__ W1T,
    const float* __restrict__ potgint, float* __restrict__ out) {
  __shared__ float s_lds[HN];
  __shared__ float gl[256];
  __shared__ float red1[4], red2[4];
  int s = blockIdx.x, tid = threadIdx.x;
  float p1 = 0.f, p2 = 0.f;
  #pragma unroll
  for (int cc = 0; cc < 4; ++cc) {
    int j = tid + cc * 256;
    float wv = wbuf[s * HN + j];
    p1 += a1[s * HN + j] * wv;
    p2 += dcoef[s * HN + j] * q[s * HN + j];
    s_lds[j] = t1f[s * HN + j] * wv;
  }
  __syncthreads();
  int part = tid >> 6, a = tid & 63;
  float gp = 0.f;
  for (int jj = part * 256; jj < part * 256 + 256; ++jj)
    gp += s_lds[jj] * W1T[jj * AN + a];
  gl[tid] = gp;
  #pragma unroll
  for (int o = 32; o > 0; o >>= 1) { p1 += __shfl_down(p1, o, 64); p2 += __shfl_down(p2, o, 64); }
  if ((tid & 63) == 0) { red1[tid >> 6] = p1; red2[tid >> 6] = p2; }
  __syncthreads();
  if (tid < 64) {
    float g = gl[tid] + gl[64 + tid] + gl[128 + tid] + gl[192 + tid];
    float sq = g * g;
    #pragma unroll
    for (int o = 32; o > 0; o >>= 1) sq += __shfl_down(sq, o, 64);
    if (tid == 0) {
      float T1 = -2.f * (red1[0] + red1[1] + red1[2] + red1[3]);
      float T2 = red2[0] + red2[1] + red2[2] + red2[3];
      out[s] = -0.5f * (T1 + T2 + sq) + potgint[s];
    }
  }
}

// ---------------------------------------------------------------------------
extern "C" void kernel_launch(void* const* d_in, const int* in_sizes, int n_in,
                              void* d_out, int out_size, void* d_ws, size_t ws_size,
                              hipStream_t stream) {
  const float* x  = (const float*)d_in[0];
  const float* W1 = (const float*)d_in[1];
  const float* b1 = (const float*)d_in[2];
  const float* W2 = (const float*)d_in[3];
  const float* b2 = (const float*)d_in[4];
  const float* W3 = (const float*)d_in[5];
  float* out = (float*)d_out;

  char* ws = (char*)d_ws;
  size_t off = 0;
  auto alloc = [&](size_t bytes) -> void* {
    void* p = ws + off; off += (bytes + 255) & ~(size_t)255; return p;
  };
  unsigned short* W2T  = (unsigned short*)alloc((size_t)HN * HN * 2);
  unsigned short* W2bf = (unsigned short*)alloc((size_t)HN * HN * 2);
  unsigned char*  W2T8 = (unsigned char*)alloc((size_t)HN * HN);
  float*          W1T  = (float*)alloc((size_t)AN * HN * 4);
  unsigned short* h1bf = (unsigned short*)alloc((size_t)BN * HN * 2);
  float*          t1f  = (float*)alloc((size_t)BN * HN * 4);
  float*          a1   = (float*)alloc((size_t)BN * HN * 4);
  float*          dcoef= (float*)alloc((size_t)BN * HN * 4);
  unsigned short* vbf  = (unsigned short*)alloc((size_t)BN * HN * 2);
  float*          wbuf = (float*)alloc((size_t)BN * HN * 4);
  float*          q    = (float*)alloc((size_t)BN * HN * 4);
  float*          pg   = (float*)alloc((size_t)BN * 4);
  // full-batch fp8 P buffer: 512 samples x 64 x 1024 = 33.5 MB
  unsigned char*  Pbf8 = (unsigned char*)alloc((size_t)BN * AN * HN);

  static bool attrSet = false;
  if (!attrSet) {
    hipFuncSetAttribute((const void*)k_big8,
                        hipFuncAttributeMaxDynamicSharedMemorySize, 65536);
    attrSet = true;
  }

  k_fwd1<<<dim3(BN), 256, 0, stream>>>(x, W1, b1, h1bf, t1f, a1, pg);
  k_packprep<<<dim3(256 + 256 + 16), 256, 0, stream>>>(W1, t1f, W2,
                                                       Pbf8, W2T, W2bf, W2T8, W1T);
  k_z2<<<dim3(HN / 64, BN / 16), 256, 0, stream>>>(h1bf, W2T, b2, W3, dcoef, vbf);
  k_w<<<dim3(HN / 64, BN / 16), 256, 0, stream>>>(vbf, W2bf, wbuf);
  k_big8<<<dim3(512), 512, 65536, stream>>>(Pbf8, W2T8, q);
  k_fin<<<dim3(BN), 256, 0, stream>>>(wbuf, a1, dcoef, q, t1f, W1T, pg, out);
}

// Round 9
// 179.734 us; speedup vs baseline: 3.4819x; 1.0898x over previous
//
#include <hip/hip_runtime.h>
#include <hip/hip_bf16.h>
#include <hip/hip_fp8.h>
#include <stdint.h>

// Problem constants
#define AN 64
#define HN 1024
#define BN 512
#define GAUSS_CONST (-3.989422804014327f)   // V0 / (sqrt(2*pi)*sigma0)
#define INV_2SIG2 2.0f

typedef __attribute__((ext_vector_type(8))) short short8;
typedef __attribute__((ext_vector_type(4))) short short4v;
typedef __attribute__((ext_vector_type(4))) float floatx4;

__device__ inline unsigned short f2bf(float f) {
  __hip_bfloat16 h = __float2bfloat16(f);        // RNE
  return *reinterpret_cast<unsigned short*>(&h);
}

__device__ inline unsigned char f2fp8(float f) {
  __hip_fp8_e4m3 t(f);                           // OCP e4m3, RNE-sat
  return (unsigned char)t.__x;
}

__device__ inline void gload_lds16(const void* g, void* l) {
  __builtin_amdgcn_global_load_lds(
      (const __attribute__((address_space(1))) void*)g,
      (__attribute__((address_space(3))) void*)l, 16, 0, 0);
}

#define PH_BAR  asm volatile("s_barrier" ::: "memory")
#define WAITV3  asm volatile("s_waitcnt vmcnt(3)" ::: "memory")

// ---------------------------------------------------------------------------
// k1 (grid-sectioned, all sections depend only on kernel inputs):
//  b < 512       : per-sample: layer-1 fwd (h1,t1,a1) + pot/gint + P fp8 pack
//                  (t1 handed off via LDS; W1 re-read, L2-hot)
//  512 <= b<768  : W2 64x64 tile -> W2bf (cast) + W2T (bf16 T) + W2T8 (fp8 T, x16)
//  768 <= b<784  : W1 64x64 tile -> W1T (f32 T)
__global__ __launch_bounds__(256) void k1(
    const float* __restrict__ x, const float* __restrict__ W1,
    const float* __restrict__ b1, const float* __restrict__ W2,
    unsigned short* __restrict__ h1bf, float* __restrict__ t1f,
    float* __restrict__ a1, float* __restrict__ potgint,
    unsigned char* __restrict__ Pbf8, unsigned short* __restrict__ W2T,
    unsigned short* __restrict__ W2bf, unsigned char* __restrict__ W2T8,
    float* __restrict__ W1T) {
  __shared__ float tile[64][65];               // transpose sections
  __shared__ float t1s[HN];                    // sample section handoff
  __shared__ float xs[AN];
  __shared__ float red[4];
  int b = blockIdx.x, tid = threadIdx.x;
  if (b < BN) {
    int s = b;
    if (tid < AN) xs[tid] = x[s * AN + tid];
    __syncthreads();
    #pragma unroll
    for (int cc = 0; cc < 4; ++cc) {
      int j = tid + cc * 256;
      float z = b1[j];
      float cs = 0.f;                          // c_j inline
      #pragma unroll 8
      for (int a = 0; a < AN; ++a) {
        float wv = W1[a * HN + j];
        z += xs[a] * wv;
        cs += wv * wv;
      }
      float h = tanhf(z), t = 1.f - h * h;
      h1bf[s * HN + j] = f2bf(h);
      t1f[s * HN + j] = t;
      a1[s * HN + j] = cs * h * t;
      t1s[j] = t;
    }
    // pot + gint
    float val = 0.f;
    #pragma unroll
    for (int p = 0; p < 16; ++p) {
      int idx = tid + p * 256;
      int i = idx >> 6, jj = idx & 63;
      if (jj > i) { float d = xs[i] - xs[jj]; val += __expf(-INV_2SIG2 * d * d); }
    }
    val *= GAUSS_CONST;
    if (tid < AN) val += 0.5f * xs[tid] * xs[tid];
    #pragma unroll
    for (int o = 32; o > 0; o >>= 1) val += __shfl_down(val, o, 64);
    if ((tid & 63) == 0) red[tid >> 6] = val;
    __syncthreads();                           // also covers t1s
    if (tid == 0) potgint[s] = red[0] + red[1] + red[2] + red[3];
    // P pack: P8[(s*64+a)][j] = fp8(8 * W1[a,j] * t1s[j])
    int j4 = tid * 4;
    floatx4 tv = *reinterpret_cast<const floatx4*>(&t1s[j4]);
    size_t outBase = ((size_t)s * 64) * HN + j4;
    for (int a = 0; a < AN; ++a) {
      floatx4 w = *reinterpret_cast<const floatx4*>(&W1[(size_t)a * HN + j4]);
      unsigned p = (unsigned)f2fp8(w[0] * tv[0] * 8.f)
                 | ((unsigned)f2fp8(w[1] * tv[1] * 8.f) << 8)
                 | ((unsigned)f2fp8(w[2] * tv[2] * 8.f) << 16)
                 | ((unsigned)f2fp8(w[3] * tv[3] * 8.f) << 24);
      *reinterpret_cast<unsigned*>(&Pbf8[outBase + (size_t)a * HN]) = p;
    }
  } else if (b < BN + 256) {
    int t = b - BN;
    int jt = (t >> 4) * 64, kt = (t & 15) * 64;
    #pragma unroll
    for (int it = 0; it < 4; ++it) {
      int e = it * 256 + tid;
      int r = e >> 4, cv = (e & 15) * 4;
      floatx4 v = *reinterpret_cast<const floatx4*>(&W2[(size_t)(jt + r) * HN + kt + cv]);
      tile[r][cv] = v[0]; tile[r][cv + 1] = v[1];
      tile[r][cv + 2] = v[2]; tile[r][cv + 3] = v[3];
      short4v o;
      #pragma unroll
      for (int i = 0; i < 4; ++i) o[i] = (short)f2bf(v[i]);
      *reinterpret_cast<short4v*>(&W2bf[(size_t)(jt + r) * HN + kt + cv]) = o;
    }
    __syncthreads();
    #pragma unroll
    for (int it = 0; it < 4; ++it) {
      int e = it * 256 + tid;
      int r = e >> 4, cv = (e & 15) * 4;     // r: k-row, cv: j-cols
      float v0 = tile[cv][r], v1 = tile[cv + 1][r];
      float v2 = tile[cv + 2][r], v3 = tile[cv + 3][r];
      short4v o;
      o[0] = (short)f2bf(v0); o[1] = (short)f2bf(v1);
      o[2] = (short)f2bf(v2); o[3] = (short)f2bf(v3);
      *reinterpret_cast<short4v*>(&W2T[(size_t)(kt + r) * HN + jt + cv]) = o;
      unsigned p8 = (unsigned)f2fp8(v0 * 16.f)
                  | ((unsigned)f2fp8(v1 * 16.f) << 8)
                  | ((unsigned)f2fp8(v2 * 16.f) << 16)
                  | ((unsigned)f2fp8(v3 * 16.f) << 24);
      *reinterpret_cast<unsigned*>(&W2T8[(size_t)(kt + r) * HN + jt + cv]) = p8;
    }
  } else {
    int t = b - (BN + 256);                    // 0..15
    int j0 = t * 64;
    #pragma unroll
    for (int it = 0; it < 4; ++it) {
      int e = it * 256 + tid;
      int r = e >> 4, cv = (e & 15) * 4;
      floatx4 v = *reinterpret_cast<const floatx4*>(&W1[(size_t)r * HN + j0 + cv]);
      tile[r][cv] = v[0]; tile[r][cv + 1] = v[1];
      tile[r][cv + 2] = v[2]; tile[r][cv + 3] = v[3];
    }
    __syncthreads();
    #pragma unroll
    for (int it = 0; it < 4; ++it) {
      int e = it * 256 + tid;
      int r = e >> 4, cv = (e & 15) * 4;
      floatx4 o;
      #pragma unroll
      for (int i = 0; i < 4; ++i) o[i] = tile[cv + i][r];
      *reinterpret_cast<floatx4*>(&W1T[(size_t)(j0 + r) * AN + cv]) = o;
    }
  }
}

// ---------------------------------------------------------------------------
// z2 = h1 @ W2 + b2 -> dcoef = -2 h2 t2 W3, v = t2*W3 (bf16)
__global__ __launch_bounds__(256) void k_z2(
    const unsigned short* __restrict__ h1bf, const unsigned short* __restrict__ W2T,
    const float* __restrict__ b2, const float* __restrict__ W3,
    float* __restrict__ dcoef, unsigned short* __restrict__ vbf) {
  __shared__ float redL[4 * 16 * 64];
  int n0 = blockIdx.x * 64, m0 = blockIdx.y * 16;
  int tid = threadIdx.x, w = tid >> 6, l = tid & 63, lr = l & 15, kg = l >> 4;
  floatx4 acc[4];
  #pragma unroll
  for (int nf = 0; nf < 4; ++nf) acc[nf] = (floatx4){0.f, 0.f, 0.f, 0.f};
  int arow = m0 + lr;
  for (int kt = 0; kt < 8; ++kt) {
    int kb = w * 256 + kt * 32 + kg * 8;
    short8 af = *reinterpret_cast<const short8*>(&h1bf[arow * HN + kb]);
    #pragma unroll
    for (int nf = 0; nf < 4; ++nf) {
      short8 bf_ = *reinterpret_cast<const short8*>(&W2T[(n0 + nf * 16 + lr) * HN + kb]);
      acc[nf] = __builtin_amdgcn_mfma_f32_16x16x32_bf16(af, bf_, acc[nf], 0, 0, 0);
    }
  }
  #pragma unroll
  for (int nf = 0; nf < 4; ++nf)
    #pragma unroll
    for (int r = 0; r < 4; ++r)
      redL[w * 1024 + (kg * 4 + r) * 64 + nf * 16 + lr] = acc[nf][r];
  __syncthreads();
  #pragma unroll
  for (int t = 0; t < 4; ++t) {
    int e = tid + t * 256;
    float z = redL[e] + redL[1024 + e] + redL[2048 + e] + redL[3072 + e];
    int row = e >> 6, col = e & 63;
    int s = m0 + row, k2 = n0 + col;
    z += b2[k2];
    float h = tanhf(z), tt = 1.f - h * h, w3 = W3[k2];
    dcoef[s * HN + k2] = -2.f * h * tt * w3;
    vbf[s * HN + k2] = f2bf(tt * w3);
  }
}

// ---------------------------------------------------------------------------
// k_bigw (512-thread blocks, 80 KB dyn LDS):
//  bid < 512 : BIG fp8 GEMM section, 8-phase with A 3-slot ring.
//  bid >= 512: w = v @ W2^T section (256 blocks, 8-wave split-K, 16s x 128c).
//
// BIG: q[s,k] = sum_a M[a,k]^2, M = P[s]@W2 (x8/x16 scales, /16384 epilogue).
// BM=256 x BN=256, BK=64 (2 k-halves). LDS: A ring 3x16KB + B dbuf 2x16KB.
// Issue schedule per tile t: ph0: B(t+1,k0); ph2: B(t+1,k1) THEN A(t+2,k0/k1)
// (B-before-A so B-drains never force-drain young A; vmcnt drains in order).
// Waits: WAITV3 at ph1 and ph3 only (induction-verified; steady in-flight<=6).
// A cover 5 phases (~500cy), B cover 3 (L2 ~200cy ok). WAR: all ring/dbuf
// overwrites issue >=1 barrier after last read of old data.
__global__ __launch_bounds__(512, 2) void k_bigw(
    const unsigned char* __restrict__ Pbf8,   // [32768][HN] fp8
    const unsigned char* __restrict__ W2T8,   // [1024][1024] fp8
    float* __restrict__ q,
    const unsigned short* __restrict__ vbf, const unsigned short* __restrict__ W2bf,
    float* __restrict__ wbuf) {
  extern __shared__ unsigned char sm8[];
  int bid = blockIdx.x;
  int tid = threadIdx.x;

  if (bid < 512) {
    // ---- BIG section ----
    int xcd = bid & 7, local = bid >> 3;
    int px = local & 3;                        // col panel (fastest, same XCD)
    int py = xcd * 16 + (local >> 2);          // XCD-exclusive A range

    int wid = tid >> 6, l = tid & 63;
    int lr = l & 15, kg = l >> 4;
    int wr = wid >> 2, wc = wid & 3;
    int wr128 = wr * 128, wc64 = wc * 64;
    int sl8 = ((kg ^ (((lr >> 2) & 1) << 1)) * 8);   // 16B-chunk XOR swizzle

    int srow = tid >> 1;
    int soff = (((tid & 1) ^ ((tid >> 3) & 1)) << 4); // pre-swizzled source
    const unsigned char* aSrc = &Pbf8[(size_t)(py * 256 + srow) * HN + soff];
    const unsigned char* bSrc = &W2T8[(size_t)(px * 256 + srow) * HN + soff];

    auto stA = [&](int slot, int tt, int kh) {
      gload_lds16(aSrc + tt * 64 + kh * 32, &sm8[slot * 16384 + kh * 8192 + tid * 16]);
    };
    auto stB = [&](int buf, int tt, int kh) {
      gload_lds16(bSrc + tt * 64 + kh * 32, &sm8[49152 + buf * 16384 + kh * 8192 + tid * 16]);
    };

    floatx4 acc[8][4];
    #pragma unroll
    for (int m = 0; m < 8; ++m)
      #pragma unroll
      for (int n = 0; n < 4; ++n) acc[m][n] = (floatx4){0.f, 0.f, 0.f, 0.f};

    long af[8], bfr[2];
    auto ldA = [&](int slot, int kh) {
      const unsigned char* Ap = &sm8[slot * 16384 + kh * 8192];
      #pragma unroll
      for (int m = 0; m < 8; ++m)
        af[m] = *reinterpret_cast<const long*>(&Ap[(wr128 + m * 16 + lr) * 32 + sl8]);
    };
    auto ldB = [&](int buf, int kh, int nh) {
      const unsigned char* Bp = &sm8[49152 + buf * 16384 + kh * 8192];
      #pragma unroll
      for (int n = 0; n < 2; ++n)
        bfr[n] = *reinterpret_cast<const long*>(&Bp[(wc64 + (nh * 2 + n) * 16 + lr) * 32 + sl8]);
    };
    auto mm = [&](int nh) {
      __builtin_amdgcn_s_setprio(1);
      #pragma unroll
      for (int m = 0; m < 8; ++m)
        #pragma unroll
        for (int n = 0; n < 2; ++n)
          acc[m][nh * 2 + n] = __builtin_amdgcn_mfma_f32_16x16x32_fp8_fp8(
              af[m], bfr[n], acc[m][nh * 2 + n], 0, 0, 0);
      __builtin_amdgcn_s_setprio(0);
    };

    // prologue: A(0,k0),A(0,k1),B(0,k0),B(0,k1),A(1,k0),A(1,k1); drain 3 oldest
    stA(0, 0, 0); stA(0, 0, 1); stB(0, 0, 0); stB(0, 0, 1);
    stA(1, 1, 0); stA(1, 1, 1);
    WAITV3; PH_BAR;

    int rs = 0;                                // t % 3
    for (int t = 0; t < 16; ++t) {
      int rb = t & 1, wb = rb ^ 1;
      int ws = rs + 2; if (ws >= 3) ws -= 3;   // (t+2) % 3
      int ta = (t + 2 < 16) ? t + 2 : 15;      // clamped prefetch (dup is L2-hot)
      int tb = (t + 1 < 16) ? t + 1 : 15;
      // ph0: reads guaranteed by (t-1).ph3's WAITV3
      ldA(rs, 0); ldB(rb, 0, 0);
      stB(wb, tb, 0);
      PH_BAR; mm(0); PH_BAR;
      // ph1
      ldB(rb, 0, 1);
      WAITV3;                                  // drains B(t,k1) for ph2
      PH_BAR; mm(1); PH_BAR;
      // ph2
      ldA(rs, 1); ldB(rb, 1, 0);
      stB(wb, tb, 1); stA(ws, ta, 0); stA(ws, ta, 1);
      PH_BAR; mm(0); PH_BAR;
      // ph3
      ldB(rb, 1, 1);
      WAITV3;                                  // drains A(t+1,*), B(t+1,k0)
      PH_BAR; mm(1); PH_BAR;
      rs = (rs + 1 == 3) ? 0 : rs + 1;
    }

    // epilogue: q[s,col] = sum over 64 a-rows of M'^2 / 16384
    int colBase = px * 256 + wc64;
    #pragma unroll
    for (int half = 0; half < 2; ++half) {
      int sOut = py * 4 + wr * 2 + half;
      #pragma unroll
      for (int nf = 0; nf < 4; ++nf) {
        float v = 0.f;
        #pragma unroll
        for (int mf = half * 4; mf < half * 4 + 4; ++mf)
          #pragma unroll
          for (int r = 0; r < 4; ++r) v += acc[mf][nf][r] * acc[mf][nf][r];
        v += __shfl_xor(v, 16, 64);
        v += __shfl_xor(v, 32, 64);
        v *= (1.f / 16384.f);
        if (l < 16) q[(size_t)sOut * HN + colBase + nf * 16 + l] = v;
      }
    }
  } else {
    // ---- w section: w[s,j] = sum_k v[s,k] W2[j,k]; 16 s x 128 cols/block ----
    float* redF = reinterpret_cast<float*>(sm8);   // 8 x 16 x 64 = 32 KB
    int wi = bid - 512;
    int m0 = (wi >> 3) * 16, n0 = (wi & 7) * 128;
    int w = tid >> 6, l = tid & 63, lr = l & 15, kg = l >> 4;
    int ks = w >> 1, ch = w & 1;
    floatx4 acc[4];
    #pragma unroll
    for (int nf = 0; nf < 4; ++nf) acc[nf] = (floatx4){0.f, 0.f, 0.f, 0.f};
    int arow = m0 + lr;
    for (int kt = 0; kt < 8; ++kt) {
      int kb = ks * 256 + kt * 32 + kg * 8;
      short8 af = *reinterpret_cast<const short8*>(&vbf[arow * HN + kb]);
      #pragma unroll
      for (int nf = 0; nf < 4; ++nf) {
        short8 bf_ = *reinterpret_cast<const short8*>(
            &W2bf[(size_t)(n0 + ch * 64 + nf * 16 + lr) * HN + kb]);
        acc[nf] = __builtin_amdgcn_mfma_f32_16x16x32_bf16(af, bf_, acc[nf], 0, 0, 0);
      }
    }
    #pragma unroll
    for (int nf = 0; nf < 4; ++nf)
      #pragma unroll
      for (int r = 0; r < 4; ++r)
        redF[w * 1024 + (kg * 4 + r) * 64 + nf * 16 + lr] = acc[nf][r];
    __syncthreads();
    #pragma unroll
    for (int it = 0; it < 4; ++it) {
      int e = it * 512 + tid;                  // 2048 = 16 rows x 128 cols
      int row = e >> 7, col = e & 127;
      int ch2 = col >> 6, cc = col & 63;
      float z = redF[(0 * 2 + ch2) * 1024 + row * 64 + cc]
              + redF[(1 * 2 + ch2) * 1024 + row * 64 + cc]
              + redF[(2 * 2 + ch2) * 1024 + row * 64 + cc]
              + redF[(3 * 2 + ch2) * 1024 + row * 64 + cc];
      wbuf[(size_t)(m0 + row) * HN + n0 + col] = z;
    }
  }
}

// ---------------------------------------------------------------------------
// finale: per sample combine T1, T2, sum g^2, pot+gint
__global__ __launch_bounds__(256) void k_fin(
    const float* __restrict__ wbuf, const float* __restrict__ a1,
    const float* __restrict__ dcoef, const float* __restrict__ q,
    const float* __restrict__ t1f, const float* __restrict__ W1T,
    const float* __restrict__ potgint, float* __restrict__ out) {
  __shared__ float s_lds[HN];
  __shared__ float gl[256];
  __shared__ float red1[4], red2[4];
  int s = blockIdx.x, tid = threadIdx.x;
  float p1 = 0.f, p2 = 0.f;
  #pragma unroll
  for (int cc = 0; cc < 4; ++cc) {
    int j = tid + cc * 256;
    float wv = wbuf[s * HN + j];
    p1 += a1[s * HN + j] * wv;
    p2 += dcoef[s * HN + j] * q[s * HN + j];
    s_lds[j] = t1f[s * HN + j] * wv;
  }
  __syncthreads();
  int part = tid >> 6, a = tid & 63;
  float gp = 0.f;
  for (int jj = part * 256; jj < part * 256 + 256; ++jj)
    gp += s_lds[jj] * W1T[jj * AN + a];
  gl[tid] = gp;
  #pragma unroll
  for (int o = 32; o > 0; o >>= 1) { p1 += __shfl_down(p1, o, 64); p2 += __shfl_down(p2, o, 64); }
  if ((tid & 63) == 0) { red1[tid >> 6] = p1; red2[tid >> 6] = p2; }
  __syncthreads();
  if (tid < 64) {
    float g = gl[tid] + gl[64 + tid] + gl[128 + tid] + gl[192 + tid];
    float sq = g * g;
    #pragma unroll
    for (int o = 32; o > 0; o >>= 1) sq += __shfl_down(sq, o, 64);
    if (tid == 0) {
      float T1 = -2.f * (red1[0] + red1[1] + red1[2] + red1[3]);
      float T2 = red2[0] + red2[1] + red2[2] + red2[3];
      out[s] = -0.5f * (T1 + T2 + sq) + potgint[s];
    }
  }
}

// ---------------------------------------------------------------------------
extern "C" void kernel_launch(void* const* d_in, const int* in_sizes, int n_in,
                              void* d_out, int out_size, void* d_ws, size_t ws_size,
                              hipStream_t stream) {
  const float* x  = (const float*)d_in[0];
  const float* W1 = (const float*)d_in[1];
  const float* b1 = (const float*)d_in[2];
  const float* W2 = (const float*)d_in[3];
  const float* b2 = (const float*)d_in[4];
  const float* W3 = (const float*)d_in[5];
  float* out = (float*)d_out;

  char* ws = (char*)d_ws;
  size_t off = 0;
  auto alloc = [&](size_t bytes) -> void* {
    void* p = ws + off; off += (bytes + 255) & ~(size_t)255; return p;
  };
  unsigned short* W2T  = (unsigned short*)alloc((size_t)HN * HN * 2);
  unsigned short* W2bf = (unsigned short*)alloc((size_t)HN * HN * 2);
  unsigned char*  W2T8 = (unsigned char*)alloc((size_t)HN * HN);
  float*          W1T  = (float*)alloc((size_t)AN * HN * 4);
  unsigned short* h1bf = (unsigned short*)alloc((size_t)BN * HN * 2);
  float*          t1f  = (float*)alloc((size_t)BN * HN * 4);
  float*          a1   = (float*)alloc((size_t)BN * HN * 4);
  float*          dcoef= (float*)alloc((size_t)BN * HN * 4);
  unsigned short* vbf  = (unsigned short*)alloc((size_t)BN * HN * 2);
  float*          wbuf = (float*)alloc((size_t)BN * HN * 4);
  float*          q    = (float*)alloc((size_t)BN * HN * 4);
  float*          pg   = (float*)alloc((size_t)BN * 4);
  unsigned char*  Pbf8 = (unsigned char*)alloc((size_t)BN * AN * HN);  // 33.5 MB

  static bool attrSet = false;
  if (!attrSet) {
    hipFuncSetAttribute((const void*)k_bigw,
                        hipFuncAttributeMaxDynamicSharedMemorySize, 81920);
    attrSet = true;
  }

  k1<<<dim3(BN + 256 + 16), 256, 0, stream>>>(x, W1, b1, W2,
                                              h1bf, t1f, a1, pg,
                                              Pbf8, W2T, W2bf, W2T8, W1T);
  k_z2<<<dim3(HN / 64, BN / 16), 256, 0, stream>>>(h1bf, W2T, b2, W3, dcoef, vbf);
  k_bigw<<<dim3(512 + 256), 512, 81920, stream>>>(Pbf8, W2T8, q, vbf, W2bf, wbuf);
  k_fin<<<dim3(BN), 256, 0, stream>>>(wbuf, a1, dcoef, q, t1f, W1T, pg, out);
}

// Round 11
// 177.110 us; speedup vs baseline: 3.5335x; 1.0148x over previous
//
#include <hip/hip_runtime.h>
#include <hip/hip_bf16.h>
#include <hip/hip_fp8.h>
#include <stdint.h>

// Problem constants
#define AN 64
#define HN 1024
#define BN 512
#define GAUSS_CONST (-3.989422804014327f)   // V0 / (sqrt(2*pi)*sigma0)
#define INV_2SIG2 2.0f

typedef __attribute__((ext_vector_type(8))) short short8;
typedef __attribute__((ext_vector_type(4))) short short4v;
typedef __attribute__((ext_vector_type(4))) float floatx4;
typedef __attribute__((ext_vector_type(2))) long longx2;

__device__ inline unsigned short f2bf(float f) {
  __hip_bfloat16 h = __float2bfloat16(f);        // RNE
  return *reinterpret_cast<unsigned short*>(&h);
}

__device__ inline unsigned char f2fp8(float f) {
  __hip_fp8_e4m3 t(f);                           // OCP e4m3, RNE-sat
  return (unsigned char)t.__x;
}

__device__ inline void gload_lds16(const void* g, void* l) {
  __builtin_amdgcn_global_load_lds(
      (const __attribute__((address_space(1))) void*)g,
      (__attribute__((address_space(3))) void*)l, 16, 0, 0);
}

#define PH_BAR  asm volatile("s_barrier" ::: "memory")
#define WAITV2  asm volatile("s_waitcnt vmcnt(2)" ::: "memory")
#define WAITV0  asm volatile("s_waitcnt vmcnt(0)" ::: "memory")

// K-interleave permutation within a 64B K-group (fp8 GEMM operands):
// logical byte lb (0..63) -> phys = (kgc<<4)+(half<<3)+(lb&7),
// half=lb>>5, kgc=(lb>>3)&3.  Global phys chunk g (16B) then holds exactly
// lane g's MFMA fragment (both k-halves) -> one ds_read_b128 per fragment.
__device__ inline int kperm4(int j) {            // j 4-aligned, within 0..63
  return (((j >> 3) & 3) << 4) + ((j >> 5) << 3) + (j & 7);
}

// ---------------------------------------------------------------------------
// k1 (grid-sectioned, all sections depend only on kernel inputs):
//  b < 512       : per-sample layer-1 fwd (h1,t1,a1) + pot/gint + P fp8 pack
//                  (vectorized; thread owns 4 consecutive j columns)
//  512 <= b<768  : W2 64x64 tile -> W2bf (cast) + W2T (bf16 T) + W2T8 (fp8 T,
//                  x16, K-interleaved j within 64B groups)
//  768 <= b<784  : W1 64x64 tile -> W1T (f32 T)
__global__ __launch_bounds__(256) void k1(
    const float* __restrict__ x, const float* __restrict__ W1,
    const float* __restrict__ b1, const float* __restrict__ W2,
    unsigned short* __restrict__ h1bf, float* __restrict__ t1f,
    float* __restrict__ a1, float* __restrict__ potgint,
    unsigned char* __restrict__ Pbf8, unsigned short* __restrict__ W2T,
    unsigned short* __restrict__ W2bf, unsigned char* __restrict__ W2T8,
    float* __restrict__ W1T) {
  __shared__ float tile[64][65];
  __shared__ float xs[AN];
  __shared__ float red[4];
  int b = blockIdx.x, tid = threadIdx.x;
  if (b < BN) {
    int s = b;
    if (tid < AN) xs[tid] = x[s * AN + tid];
    __syncthreads();
    int j4 = tid * 4;
    floatx4 z4 = *reinterpret_cast<const floatx4*>(&b1[j4]);
    floatx4 cs4 = (floatx4){0.f, 0.f, 0.f, 0.f};
    for (int a = 0; a < AN; ++a) {
      floatx4 w = *reinterpret_cast<const floatx4*>(&W1[(size_t)a * HN + j4]);
      float xa = xs[a];
      #pragma unroll
      for (int e = 0; e < 4; ++e) { z4[e] += xa * w[e]; cs4[e] += w[e] * w[e]; }
    }
    floatx4 t4, a4; short4v h4;
    #pragma unroll
    for (int e = 0; e < 4; ++e) {
      float h = tanhf(z4[e]), t = 1.f - h * h;
      h4[e] = (short)f2bf(h);
      t4[e] = t;
      a4[e] = cs4[e] * h * t;
    }
    *reinterpret_cast<short4v*>(&h1bf[(size_t)s * HN + j4]) = h4;
    *reinterpret_cast<floatx4*>(&t1f[(size_t)s * HN + j4]) = t4;
    *reinterpret_cast<floatx4*>(&a1[(size_t)s * HN + j4]) = a4;
    // pot + gint
    float val = 0.f;
    #pragma unroll
    for (int p = 0; p < 16; ++p) {
      int idx = tid + p * 256;
      int i = idx >> 6, jj = idx & 63;
      if (jj > i) { float d = xs[i] - xs[jj]; val += __expf(-INV_2SIG2 * d * d); }
    }
    val *= GAUSS_CONST;
    if (tid < AN) val += 0.5f * xs[tid] * xs[tid];
    #pragma unroll
    for (int o = 32; o > 0; o >>= 1) val += __shfl_down(val, o, 64);
    if ((tid & 63) == 0) red[tid >> 6] = val;
    __syncthreads();
    if (tid == 0) potgint[s] = red[0] + red[1] + red[2] + red[3];
    // P pack (K-interleaved): phys offset within 64B group via kperm4
    int physOff = (j4 & ~63) + kperm4(j4 & 63);
    size_t outBase = ((size_t)s * 64) * HN + physOff;
    for (int a = 0; a < AN; ++a) {
      floatx4 w = *reinterpret_cast<const floatx4*>(&W1[(size_t)a * HN + j4]);
      unsigned p = (unsigned)f2fp8(w[0] * t4[0] * 8.f)
                 | ((unsigned)f2fp8(w[1] * t4[1] * 8.f) << 8)
                 | ((unsigned)f2fp8(w[2] * t4[2] * 8.f) << 16)
                 | ((unsigned)f2fp8(w[3] * t4[3] * 8.f) << 24);
      *reinterpret_cast<unsigned*>(&Pbf8[outBase + (size_t)a * HN]) = p;
    }
  } else if (b < BN + 256) {
    int t = b - BN;
    int jt = (t >> 4) * 64, kt = (t & 15) * 64;
    #pragma unroll
    for (int it = 0; it < 4; ++it) {
      int e = it * 256 + tid;
      int r = e >> 4, cv = (e & 15) * 4;
      floatx4 v = *reinterpret_cast<const floatx4*>(&W2[(size_t)(jt + r) * HN + kt + cv]);
      tile[r][cv] = v[0]; tile[r][cv + 1] = v[1];
      tile[r][cv + 2] = v[2]; tile[r][cv + 3] = v[3];
      short4v o;
      #pragma unroll
      for (int i = 0; i < 4; ++i) o[i] = (short)f2bf(v[i]);
      *reinterpret_cast<short4v*>(&W2bf[(size_t)(jt + r) * HN + kt + cv]) = o;
    }
    __syncthreads();
    #pragma unroll
    for (int it = 0; it < 4; ++it) {
      int e = it * 256 + tid;
      int r = e >> 4, cv = (e & 15) * 4;     // r: k2-row, cv: j-cols (0..63)
      float v0 = tile[cv][r], v1 = tile[cv + 1][r];
      float v2 = tile[cv + 2][r], v3 = tile[cv + 3][r];
      short4v o;
      o[0] = (short)f2bf(v0); o[1] = (short)f2bf(v1);
      o[2] = (short)f2bf(v2); o[3] = (short)f2bf(v3);
      *reinterpret_cast<short4v*>(&W2T[(size_t)(kt + r) * HN + jt + cv]) = o;
      unsigned p8 = (unsigned)f2fp8(v0 * 16.f)
                  | ((unsigned)f2fp8(v1 * 16.f) << 8)
                  | ((unsigned)f2fp8(v2 * 16.f) << 16)
                  | ((unsigned)f2fp8(v3 * 16.f) << 24);
      *reinterpret_cast<unsigned*>(&W2T8[(size_t)(kt + r) * HN + jt + kperm4(cv)]) = p8;
    }
  } else {
    int t = b - (BN + 256);                    // 0..15
    int j0 = t * 64;
    #pragma unroll
    for (int it = 0; it < 4; ++it) {
      int e = it * 256 + tid;
      int r = e >> 4, cv = (e & 15) * 4;
      floatx4 v = *reinterpret_cast<const floatx4*>(&W1[(size_t)r * HN + j0 + cv]);
      tile[r][cv] = v[0]; tile[r][cv + 1] = v[1];
      tile[r][cv + 2] = v[2]; tile[r][cv + 3] = v[3];
    }
    __syncthreads();
    #pragma unroll
    for (int it = 0; it < 4; ++it) {
      int e = it * 256 + tid;
      int r = e >> 4, cv = (e & 15) * 4;
      floatx4 o;
      #pragma unroll
      for (int i = 0; i < 4; ++i) o[i] = tile[cv + i][r];
      *reinterpret_cast<floatx4*>(&W1T[(size_t)(j0 + r) * AN + cv]) = o;
    }
  }
}

// ---------------------------------------------------------------------------
// z2 = h1 @ W2 + b2 -> dcoef = -2 h2 t2 W3, v = t2*W3 (bf16)
__global__ __launch_bounds__(256) void k_z2(
    const unsigned short* __restrict__ h1bf, const unsigned short* __restrict__ W2T,
    const float* __restrict__ b2, const float* __restrict__ W3,
    float* __restrict__ dcoef, unsigned short* __restrict__ vbf) {
  __shared__ float redL[4 * 16 * 64];
  int n0 = blockIdx.x * 64, m0 = blockIdx.y * 16;
  int tid = threadIdx.x, w = tid >> 6, l = tid & 63, lr = l & 15, kg = l >> 4;
  floatx4 acc[4];
  #pragma unroll
  for (int nf = 0; nf < 4; ++nf) acc[nf] = (floatx4){0.f, 0.f, 0.f, 0.f};
  int arow = m0 + lr;
  for (int kt = 0; kt < 8; ++kt) {
    int kb = w * 256 + kt * 32 + kg * 8;
    short8 af = *reinterpret_cast<const short8*>(&h1bf[arow * HN + kb]);
    #pragma unroll
    for (int nf = 0; nf < 4; ++nf) {
      short8 bf_ = *reinterpret_cast<const short8*>(&W2T[(n0 + nf * 16 + lr) * HN + kb]);
      acc[nf] = __builtin_amdgcn_mfma_f32_16x16x32_bf16(af, bf_, acc[nf], 0, 0, 0);
    }
  }
  #pragma unroll
  for (int nf = 0; nf < 4; ++nf)
    #pragma unroll
    for (int r = 0; r < 4; ++r)
      redL[w * 1024 + (kg * 4 + r) * 64 + nf * 16 + lr] = acc[nf][r];
  __syncthreads();
  #pragma unroll
  for (int t = 0; t < 4; ++t) {
    int e = tid + t * 256;
    float z = redL[e] + redL[1024 + e] + redL[2048 + e] + redL[3072 + e];
    int row = e >> 6, col = e & 63;
    int s = m0 + row, k2 = n0 + col;
    z += b2[k2];
    float h = tanhf(z), tt = 1.f - h * h, w3 = W3[k2];
    dcoef[s * HN + k2] = -2.f * h * tt * w3;
    vbf[s * HN + k2] = f2bf(tt * w3);
  }
}

// ---------------------------------------------------------------------------
// k_bigw (512-thread blocks, 80 KB dyn LDS):
//  bid < 512 : BIG fp8 GEMM, 2 phases/tile x 32 MFMA (K=64 merged via
//              K-interleaved operand layout + ds_read_b128).
//  bid >= 512: w = v @ W2^T section (256 blocks, 8-wave split-K).
//
// BIG: q[s,k] = sum_a M[a,k]^2, M = P[s]@W2 (x8/x16 scales, /16384 epilogue).
// BM=256 x BN=256, BK=64. LDS: A ring 3x16KB + B dbuf 2x16KB = 80KB.
// Row = 64B K-interleaved; lane kg reads b128 at row*64+((kg^((lr>>1)&3))<<4)
// (XOR swizzle -> 2 lanes/bank, free).
// STAGING (m104 rule: LDS dest MUST be wave-uniform base + lane*16 -- R10's
// tid*32-stride dest violated this and corrupted the tile): 2 loads/thread,
// load1 dest = base + tid*16 (rows 0..127: row=tid>>2, phys chunk=tid&3),
// load2 dest = +8192 (rows 128..255, source +128*HN). Swizzle const across
// both: s=(tid>>3)&3 invariant under +128 rows; source chunk c1=(tid&3)^s.
// Ledger: stB(t+1)@ph0, stA(t+2)@ph1, ONE WAITV2/tile at ph1 -> leaves
// A(t+2) in flight; A cover ~2 phases, B ~1 phase.
__global__ __launch_bounds__(512, 2) void k_bigw(
    const unsigned char* __restrict__ Pbf8,   // [32768][HN] fp8, K-interleaved
    const unsigned char* __restrict__ W2T8,   // [1024][1024] fp8, K-interleaved
    float* __restrict__ q,
    const unsigned short* __restrict__ vbf, const unsigned short* __restrict__ W2bf,
    float* __restrict__ wbuf) {
  extern __shared__ unsigned char sm8[];
  int bid = blockIdx.x;
  int tid = threadIdx.x;

  if (bid < 512) {
    // ---- BIG section ----
    int xcd = bid & 7, local = bid >> 3;
    int px = local & 3;                        // col panel (fastest, same XCD)
    int py = xcd * 16 + (local >> 2);          // XCD-exclusive A range

    int wid = tid >> 6, l = tid & 63;
    int lr = l & 15, kg = l >> 4;
    int wr = wid >> 2, wc = wid & 3;
    int wr128 = wr * 128, wc64 = wc * 64;
    int rdOff = ((kg ^ ((lr >> 1) & 3)) << 4); // b128 chunk (swizzled)

    // staging geometry: row r1 = tid>>2 (load1) / r1+128 (load2),
    // phys chunk p = tid&3, swizzle s = (tid>>3)&3, source chunk c1 = p^s.
    int r1 = tid >> 2;
    int c1 = (tid & 3) ^ ((tid >> 3) & 3);
    const unsigned char* aSrc = &Pbf8[(size_t)(py * 256 + r1) * HN + c1 * 16];
    const unsigned char* bSrc = &W2T8[(size_t)(px * 256 + r1) * HN + c1 * 16];

    auto stA = [&](int slot, int tt) {
      const unsigned char* s = aSrc + tt * 64;
      unsigned char* d = &sm8[slot * 16384 + tid * 16];
      gload_lds16(s, d);
      gload_lds16(s + (size_t)128 * HN, d + 8192);
    };
    auto stB = [&](int buf, int tt) {
      const unsigned char* s = bSrc + tt * 64;
      unsigned char* d = &sm8[49152 + buf * 16384 + tid * 16];
      gload_lds16(s, d);
      gload_lds16(s + (size_t)128 * HN, d + 8192);
    };

    floatx4 acc[8][4];
    #pragma unroll
    for (int m = 0; m < 8; ++m)
      #pragma unroll
      for (int n = 0; n < 4; ++n) acc[m][n] = (floatx4){0.f, 0.f, 0.f, 0.f};

    longx2 af[8], bfr[2];
    auto ldA = [&](int slot) {
      const unsigned char* Ap = &sm8[slot * 16384];
      #pragma unroll
      for (int m = 0; m < 8; ++m)
        af[m] = *reinterpret_cast<const longx2*>(&Ap[(wr128 + m * 16 + lr) * 64 + rdOff]);
    };
    auto ldB = [&](int buf, int nh) {
      const unsigned char* Bp = &sm8[49152 + buf * 16384];
      #pragma unroll
      for (int n = 0; n < 2; ++n)
        bfr[n] = *reinterpret_cast<const longx2*>(
            &Bp[(wc64 + (nh * 2 + n) * 16 + lr) * 64 + rdOff]);
    };
    auto mm = [&](int nh) {
      __builtin_amdgcn_s_setprio(1);
      #pragma unroll
      for (int m = 0; m < 8; ++m)
        #pragma unroll
        for (int n = 0; n < 2; ++n) {
          acc[m][nh * 2 + n] = __builtin_amdgcn_mfma_f32_16x16x32_fp8_fp8(
              af[m].x, bfr[n].x, acc[m][nh * 2 + n], 0, 0, 0);
          acc[m][nh * 2 + n] = __builtin_amdgcn_mfma_f32_16x16x32_fp8_fp8(
              af[m].y, bfr[n].y, acc[m][nh * 2 + n], 0, 0, 0);
        }
      __builtin_amdgcn_s_setprio(0);
    };

    // prologue: A(0)->slot0, B(0)->buf0, A(1)->slot1 (6 loads); drain 4 oldest
    stA(0, 0); stB(0, 0); stA(1, 1);
    WAITV2; PH_BAR;

    int rs = 0;                                // t % 3
    for (int t = 0; t < 16; ++t) {
      int rb = t & 1, wb = rb ^ 1;
      int ws = rs + 2; if (ws >= 3) ws -= 3;
      int tb = (t + 1 < 16) ? t + 1 : 15;
      int ta = (t + 2 < 16) ? t + 2 : 15;
      // ph0 (nh=0): reads drained by prev tile's WAITV2 + barrier
      ldA(rs); ldB(rb, 0);
      stB(wb, tb);
      PH_BAR; mm(0); PH_BAR;
      // ph1 (nh=1)
      ldB(rb, 1);
      stA(ws, ta);
      WAITV2;                                  // leaves A(t+2); drains A(t+1),B(t+1)
      PH_BAR; mm(1); PH_BAR;
      rs = (rs + 1 == 3) ? 0 : rs + 1;
    }
    WAITV0;                                    // drain tail duplicates

    // epilogue: q[s,col] = sum over 64 a-rows of M'^2 / 16384
    int colBase = px * 256 + wc64;
    #pragma unroll
    for (int half = 0; half < 2; ++half) {
      int sOut = py * 4 + wr * 2 + half;
      #pragma unroll
      for (int nf = 0; nf < 4; ++nf) {
        float v = 0.f;
        #pragma unroll
        for (int mf = half * 4; mf < half * 4 + 4; ++mf)
          #pragma unroll
          for (int r = 0; r < 4; ++r) v += acc[mf][nf][r] * acc[mf][nf][r];
        v += __shfl_xor(v, 16, 64);
        v += __shfl_xor(v, 32, 64);
        v *= (1.f / 16384.f);
        if (l < 16) q[(size_t)sOut * HN + colBase + nf * 16 + l] = v;
      }
    }
  } else {
    // ---- w section: w[s,j] = sum_k v[s,k] W2[j,k]; 16 s x 128 cols/block ----
    float* redF = reinterpret_cast<float*>(sm8);   // 8 x 16 x 64 = 32 KB
    int wi = bid - 512;
    int m0 = (wi >> 3) * 16, n0 = (wi & 7) * 128;
    int w = tid >> 6, l = tid & 63, lr = l & 15, kg = l >> 4;
    int ks = w >> 1, ch = w & 1;
    floatx4 acc[4];
    #pragma unroll
    for (int nf = 0; nf < 4; ++nf) acc[nf] = (floatx4){0.f, 0.f, 0.f, 0.f};
    int arow = m0 + lr;
    for (int kt = 0; kt < 8; ++kt) {
      int kb = ks * 256 + kt * 32 + kg * 8;
      short8 af = *reinterpret_cast<const short8*>(&vbf[arow * HN + kb]);
      #pragma unroll
      for (int nf = 0; nf < 4; ++nf) {
        short8 bf_ = *reinterpret_cast<const short8*>(
            &W2bf[(size_t)(n0 + ch * 64 + nf * 16 + lr) * HN + kb]);
        acc[nf] = __builtin_amdgcn_mfma_f32_16x16x32_bf16(af, bf_, acc[nf], 0, 0, 0);
      }
    }
    #pragma unroll
    for (int nf = 0; nf < 4; ++nf)
      #pragma unroll
      for (int r = 0; r < 4; ++r)
        redF[w * 1024 + (kg * 4 + r) * 64 + nf * 16 + lr] = acc[nf][r];
    __syncthreads();
    #pragma unroll
    for (int it = 0; it < 4; ++it) {
      int e = it * 512 + tid;                  // 2048 = 16 rows x 128 cols
      int row = e >> 7, col = e & 127;
      int ch2 = col >> 6, cc = col & 63;
      float z = redF[(0 * 2 + ch2) * 1024 + row * 64 + cc]
              + redF[(1 * 2 + ch2) * 1024 + row * 64 + cc]
              + redF[(2 * 2 + ch2) * 1024 + row * 64 + cc]
              + redF[(3 * 2 + ch2) * 1024 + row * 64 + cc];
      wbuf[(size_t)(m0 + row) * HN + n0 + col] = z;
    }
  }
}

// ---------------------------------------------------------------------------
// finale: per sample combine T1, T2, sum g^2, pot+gint
__global__ __launch_bounds__(256) void k_fin(
    const float* __restrict__ wbuf, const float* __restrict__ a1,
    const float* __restrict__ dcoef, const float* __restrict__ q,
    const float* __restrict__ t1f, const float* __restrict__ W1T,
    const float* __restrict__ potgint, float* __restrict__ out) {
  __shared__ float s_lds[HN];
  __shared__ float gl[256];
  __shared__ float red1[4], red2[4];
  int s = blockIdx.x, tid = threadIdx.x;
  float p1 = 0.f, p2 = 0.f;
  #pragma unroll
  for (int cc = 0; cc < 4; ++cc) {
    int j = tid + cc * 256;
    float wv = wbuf[s * HN + j];
    p1 += a1[s * HN + j] * wv;
    p2 += dcoef[s * HN + j] * q[s * HN + j];
    s_lds[j] = t1f[s * HN + j] * wv;
  }
  __syncthreads();
  int part = tid >> 6, a = tid & 63;
  float gp = 0.f;
  for (int jj = part * 256; jj < part * 256 + 256; ++jj)
    gp += s_lds[jj] * W1T[jj * AN + a];
  gl[tid] = gp;
  #pragma unroll
  for (int o = 32; o > 0; o >>= 1) { p1 += __shfl_down(p1, o, 64); p2 += __shfl_down(p2, o, 64); }
  if ((tid & 63) == 0) { red1[tid >> 6] = p1; red2[tid >> 6] = p2; }
  __syncthreads();
  if (tid < 64) {
    float g = gl[tid] + gl[64 + tid] + gl[128 + tid] + gl[192 + tid];
    float sq = g * g;
    #pragma unroll
    for (int o = 32; o > 0; o >>= 1) sq += __shfl_down(sq, o, 64);
    if (tid == 0) {
      float T1 = -2.f * (red1[0] + red1[1] + red1[2] + red1[3]);
      float T2 = red2[0] + red2[1] + red2[2] + red2[3];
      out[s] = -0.5f * (T1 + T2 + sq) + potgint[s];
    }
  }
}

// ---------------------------------------------------------------------------
extern "C" void kernel_launch(void* const* d_in, const int* in_sizes, int n_in,
                              void* d_out, int out_size, void* d_ws, size_t ws_size,
                              hipStream_t stream) {
  const float* x  = (const float*)d_in[0];
  const float* W1 = (const float*)d_in[1];
  const float* b1 = (const float*)d_in[2];
  const float* W2 = (const float*)d_in[3];
  const float* b2 = (const float*)d_in[4];
  const float* W3 = (const float*)d_in[5];
  float* out = (float*)d_out;

  char* ws = (char*)d_ws;
  size_t off = 0;
  auto alloc = [&](size_t bytes) -> void* {
    void* p = ws + off; off += (bytes + 255) & ~(size_t)255; return p;
  };
  unsigned short* W2T  = (unsigned short*)alloc((size_t)HN * HN * 2);
  unsigned short* W2bf = (unsigned short*)alloc((size_t)HN * HN * 2);
  unsigned char*  W2T8 = (unsigned char*)alloc((size_t)HN * HN);
  float*          W1T  = (float*)alloc((size_t)AN * HN * 4);
  unsigned short* h1bf = (unsigned short*)alloc((size_t)BN * HN * 2);
  float*          t1f  = (float*)alloc((size_t)BN * HN * 4);
  float*          a1   = (float*)alloc((size_t)BN * HN * 4);
  float*          dcoef= (float*)alloc((size_t)BN * HN * 4);
  unsigned short* vbf  = (unsigned short*)alloc((size_t)BN * HN * 2);
  float*          wbuf = (float*)alloc((size_t)BN * HN * 4);
  float*          q    = (float*)alloc((size_t)BN * HN * 4);
  float*          pg   = (float*)alloc((size_t)BN * 4);
  unsigned char*  Pbf8 = (unsigned char*)alloc((size_t)BN * AN * HN);  // 33.5 MB

  static bool attrSet = false;
  if (!attrSet) {
    hipFuncSetAttribute((const void*)k_bigw,
                        hipFuncAttributeMaxDynamicSharedMemorySize, 81920);
    attrSet = true;
  }

  k1<<<dim3(BN + 256 + 16), 256, 0, stream>>>(x, W1, b1, W2,
                                              h1bf, t1f, a1, pg,
                                              Pbf8, W2T, W2bf, W2T8, W1T);
  k_z2<<<dim3(HN / 64, BN / 16), 256, 0, stream>>>(h1bf, W2T, b2, W3, dcoef, vbf);
  k_bigw<<<dim3(512 + 256), 512, 81920, stream>>>(Pbf8, W2T8, q, vbf, W2bf, wbuf);
  k_fin<<<dim3(BN), 256, 0, stream>>>(wbuf, a1, dcoef, q, t1f, W1T, pg, out);
}

// Round 12
// 173.236 us; speedup vs baseline: 3.6126x; 1.0224x over previous
//
#include <hip/hip_runtime.h>
#include <hip/hip_bf16.h>
#include <stdint.h>

// Problem constants
#define AN 64
#define HN 1024
#define BN 512
#define GAUSS_CONST (-3.989422804014327f)   // V0 / (sqrt(2*pi)*sigma0)
#define INV_2SIG2 2.0f

// int8 quant scales for the big GEMM (headroom-checked: |P|<=~0.53 -> 102,
// |W2|<=~0.16 -> 123; clamp +-127 guards tails; i32 accum exact)
#define SA 192.0f
#define SB 768.0f
#define INVQ (1.0f / (SA * SB))

typedef __attribute__((ext_vector_type(8))) short short8;
typedef __attribute__((ext_vector_type(4))) short short4v;
typedef __attribute__((ext_vector_type(4))) float floatx4;
typedef __attribute__((ext_vector_type(4))) int intx4;

__device__ inline unsigned short f2bf(float f) {
  __hip_bfloat16 h = __float2bfloat16(f);        // RNE
  return *reinterpret_cast<unsigned short*>(&h);
}

__device__ inline unsigned q8(float x, float s) {  // clamp+RNE to int8 byte
  float xc = fminf(fmaxf(x * s, -127.f), 127.f);
  int qi = (int)rintf(xc);
  return (unsigned)(qi & 255);
}

__device__ inline void gload_lds16(const void* g, void* l) {
  __builtin_amdgcn_global_load_lds(
      (const __attribute__((address_space(1))) void*)g,
      (__attribute__((address_space(3))) void*)l, 16, 0, 0);
}

#define PH_BAR  asm volatile("s_barrier" ::: "memory")
#define WAITV2  asm volatile("s_waitcnt vmcnt(2)" ::: "memory")
#define WAITV0  asm volatile("s_waitcnt vmcnt(0)" ::: "memory")

// ---------------------------------------------------------------------------
// k1 (grid-sectioned, all sections depend only on kernel inputs):
//  b < 512       : per-sample layer-1 fwd (h1,t1,a1) + pot/gint + P i8 pack
//  512 <= b<768  : W2 64x64 tile -> W2bf (cast) + W2T (bf16 T) + W2Ti8 (i8 T,
//                  x768, LINEAR layout)
//  768 <= b<784  : W1 64x64 tile -> W1T (f32 T)
__global__ __launch_bounds__(256) void k1(
    const float* __restrict__ x, const float* __restrict__ W1,
    const float* __restrict__ b1, const float* __restrict__ W2,
    unsigned short* __restrict__ h1bf, float* __restrict__ t1f,
    float* __restrict__ a1, float* __restrict__ potgint,
    unsigned char* __restrict__ Pi8, unsigned short* __restrict__ W2T,
    unsigned short* __restrict__ W2bf, unsigned char* __restrict__ W2Ti8,
    float* __restrict__ W1T) {
  __shared__ float tile[64][65];
  __shared__ float xs[AN];
  __shared__ float red[4];
  int b = blockIdx.x, tid = threadIdx.x;
  if (b < BN) {
    int s = b;
    if (tid < AN) xs[tid] = x[s * AN + tid];
    __syncthreads();
    int j4 = tid * 4;
    floatx4 z4 = *reinterpret_cast<const floatx4*>(&b1[j4]);
    floatx4 cs4 = (floatx4){0.f, 0.f, 0.f, 0.f};
    for (int a = 0; a < AN; ++a) {
      floatx4 w = *reinterpret_cast<const floatx4*>(&W1[(size_t)a * HN + j4]);
      float xa = xs[a];
      #pragma unroll
      for (int e = 0; e < 4; ++e) { z4[e] += xa * w[e]; cs4[e] += w[e] * w[e]; }
    }
    floatx4 t4, a4; short4v h4;
    #pragma unroll
    for (int e = 0; e < 4; ++e) {
      float h = tanhf(z4[e]), t = 1.f - h * h;
      h4[e] = (short)f2bf(h);
      t4[e] = t;
      a4[e] = cs4[e] * h * t;
    }
    *reinterpret_cast<short4v*>(&h1bf[(size_t)s * HN + j4]) = h4;
    *reinterpret_cast<floatx4*>(&t1f[(size_t)s * HN + j4]) = t4;
    *reinterpret_cast<floatx4*>(&a1[(size_t)s * HN + j4]) = a4;
    // pot + gint
    float val = 0.f;
    #pragma unroll
    for (int p = 0; p < 16; ++p) {
      int idx = tid + p * 256;
      int i = idx >> 6, jj = idx & 63;
      if (jj > i) { float d = xs[i] - xs[jj]; val += __expf(-INV_2SIG2 * d * d); }
    }
    val *= GAUSS_CONST;
    if (tid < AN) val += 0.5f * xs[tid] * xs[tid];
    #pragma unroll
    for (int o = 32; o > 0; o >>= 1) val += __shfl_down(val, o, 64);
    if ((tid & 63) == 0) red[tid >> 6] = val;
    __syncthreads();
    if (tid == 0) potgint[s] = red[0] + red[1] + red[2] + red[3];
    // P pack (i8, x SA, linear layout)
    size_t outBase = ((size_t)s * 64) * HN + j4;
    for (int a = 0; a < AN; ++a) {
      floatx4 w = *reinterpret_cast<const floatx4*>(&W1[(size_t)a * HN + j4]);
      unsigned p = q8(w[0] * t4[0], SA)
                 | (q8(w[1] * t4[1], SA) << 8)
                 | (q8(w[2] * t4[2], SA) << 16)
                 | (q8(w[3] * t4[3], SA) << 24);
      *reinterpret_cast<unsigned*>(&Pi8[outBase + (size_t)a * HN]) = p;
    }
  } else if (b < BN + 256) {
    int t = b - BN;
    int jt = (t >> 4) * 64, kt = (t & 15) * 64;
    #pragma unroll
    for (int it = 0; it < 4; ++it) {
      int e = it * 256 + tid;
      int r = e >> 4, cv = (e & 15) * 4;
      floatx4 v = *reinterpret_cast<const floatx4*>(&W2[(size_t)(jt + r) * HN + kt + cv]);
      tile[r][cv] = v[0]; tile[r][cv + 1] = v[1];
      tile[r][cv + 2] = v[2]; tile[r][cv + 3] = v[3];
      short4v o;
      #pragma unroll
      for (int i = 0; i < 4; ++i) o[i] = (short)f2bf(v[i]);
      *reinterpret_cast<short4v*>(&W2bf[(size_t)(jt + r) * HN + kt + cv]) = o;
    }
    __syncthreads();
    #pragma unroll
    for (int it = 0; it < 4; ++it) {
      int e = it * 256 + tid;
      int r = e >> 4, cv = (e & 15) * 4;     // r: k2-row, cv: j-cols (0..63)
      float v0 = tile[cv][r], v1 = tile[cv + 1][r];
      float v2 = tile[cv + 2][r], v3 = tile[cv + 3][r];
      short4v o;
      o[0] = (short)f2bf(v0); o[1] = (short)f2bf(v1);
      o[2] = (short)f2bf(v2); o[3] = (short)f2bf(v3);
      *reinterpret_cast<short4v*>(&W2T[(size_t)(kt + r) * HN + jt + cv]) = o;
      unsigned p8 = q8(v0, SB) | (q8(v1, SB) << 8)
                  | (q8(v2, SB) << 16) | (q8(v3, SB) << 24);
      *reinterpret_cast<unsigned*>(&W2Ti8[(size_t)(kt + r) * HN + jt + cv]) = p8;
    }
  } else {
    int t = b - (BN + 256);                    // 0..15
    int j0 = t * 64;
    #pragma unroll
    for (int it = 0; it < 4; ++it) {
      int e = it * 256 + tid;
      int r = e >> 4, cv = (e & 15) * 4;
      floatx4 v = *reinterpret_cast<const floatx4*>(&W1[(size_t)r * HN + j0 + cv]);
      tile[r][cv] = v[0]; tile[r][cv + 1] = v[1];
      tile[r][cv + 2] = v[2]; tile[r][cv + 3] = v[3];
    }
    __syncthreads();
    #pragma unroll
    for (int it = 0; it < 4; ++it) {
      int e = it * 256 + tid;
      int r = e >> 4, cv = (e & 15) * 4;
      floatx4 o;
      #pragma unroll
      for (int i = 0; i < 4; ++i) o[i] = tile[cv + i][r];
      *reinterpret_cast<floatx4*>(&W1T[(size_t)(j0 + r) * AN + cv]) = o;
    }
  }
}

// ---------------------------------------------------------------------------
// z2 = h1 @ W2 + b2 -> dcoef = -2 h2 t2 W3, v = t2*W3 (bf16)
__global__ __launch_bounds__(256) void k_z2(
    const unsigned short* __restrict__ h1bf, const unsigned short* __restrict__ W2T,
    const float* __restrict__ b2, const float* __restrict__ W3,
    float* __restrict__ dcoef, unsigned short* __restrict__ vbf) {
  __shared__ float redL[4 * 16 * 64];
  int n0 = blockIdx.x * 64, m0 = blockIdx.y * 16;
  int tid = threadIdx.x, w = tid >> 6, l = tid & 63, lr = l & 15, kg = l >> 4;
  floatx4 acc[4];
  #pragma unroll
  for (int nf = 0; nf < 4; ++nf) acc[nf] = (floatx4){0.f, 0.f, 0.f, 0.f};
  int arow = m0 + lr;
  for (int kt = 0; kt < 8; ++kt) {
    int kb = w * 256 + kt * 32 + kg * 8;
    short8 af = *reinterpret_cast<const short8*>(&h1bf[arow * HN + kb]);
    #pragma unroll
    for (int nf = 0; nf < 4; ++nf) {
      short8 bf_ = *reinterpret_cast<const short8*>(&W2T[(n0 + nf * 16 + lr) * HN + kb]);
      acc[nf] = __builtin_amdgcn_mfma_f32_16x16x32_bf16(af, bf_, acc[nf], 0, 0, 0);
    }
  }
  #pragma unroll
  for (int nf = 0; nf < 4; ++nf)
    #pragma unroll
    for (int r = 0; r < 4; ++r)
      redL[w * 1024 + (kg * 4 + r) * 64 + nf * 16 + lr] = acc[nf][r];
  __syncthreads();
  #pragma unroll
  for (int t = 0; t < 4; ++t) {
    int e = tid + t * 256;
    float z = redL[e] + redL[1024 + e] + redL[2048 + e] + redL[3072 + e];
    int row = e >> 6, col = e & 63;
    int s = m0 + row, k2 = n0 + col;
    z += b2[k2];
    float h = tanhf(z), tt = 1.f - h * h, w3 = W3[k2];
    dcoef[s * HN + k2] = -2.f * h * tt * w3;
    vbf[s * HN + k2] = f2bf(tt * w3);
  }
}

// ---------------------------------------------------------------------------
// k_bigw (512-thread blocks, 80 KB dyn LDS):
//  bid < 512 : BIG i8 GEMM, 2 phases/tile x 16 MFMA (K=64 per instr).
//  bid >= 512: w = v @ W2^T section (256 blocks, 8-wave split-K).
//
// BIG: q[s,k] = sum_a M[a,k]^2, M = P[s]@W2 (i8 xSA/xSB, epilogue xINVQ^2).
// BM=256 x BN=256, BK=64. LDS: A ring 3x16KB + B dbuf 2x16KB = 80KB.
// Operands LINEAR: row = 64 consecutive k-bytes; lane (lr,kg) reads its
// 16x16x64-i8 fragment (k = kg*16 + i) as ONE ds_read_b128 at
// row*64 + ((kg ^ ((lr>>1)&3))<<4)  (16B-chunk XOR swizzle, 2 lanes/bank).
// Staging (m104: dest = wave-uniform + lane*16): load1 dest = base+tid*16
// (row tid>>2, phys chunk tid&3), load2 dest = +8192 (row +128). Source
// chunk c1 = (tid&3) ^ ((tid>>3)&3) (same involution as read side).
// Ledger: stB(t+1)@ph0, stA(t+2)@ph1, ONE WAITV2/tile at ph1.
__global__ __launch_bounds__(512, 2) void k_bigw(
    const unsigned char* __restrict__ Pi8,    // [32768][HN] i8, linear
    const unsigned char* __restrict__ W2Ti8,  // [1024][1024] i8, linear
    float* __restrict__ q,
    const unsigned short* __restrict__ vbf, const unsigned short* __restrict__ W2bf,
    float* __restrict__ wbuf) {
  extern __shared__ unsigned char sm8[];
  int bid = blockIdx.x;
  int tid = threadIdx.x;

  if (bid < 512) {
    // ---- BIG section ----
    int xcd = bid & 7, local = bid >> 3;
    int px = local & 3;                        // col panel (fastest, same XCD)
    int py = xcd * 16 + (local >> 2);          // XCD-exclusive A range

    int wid = tid >> 6, l = tid & 63;
    int lr = l & 15, kg = l >> 4;
    int wr = wid >> 2, wc = wid & 3;
    int wr128 = wr * 128, wc64 = wc * 64;
    int rdOff = ((kg ^ ((lr >> 1) & 3)) << 4); // b128 chunk (swizzled)

    int r1 = tid >> 2;
    int c1 = (tid & 3) ^ ((tid >> 3) & 3);
    const unsigned char* aSrc = &Pi8[(size_t)(py * 256 + r1) * HN + c1 * 16];
    const unsigned char* bSrc = &W2Ti8[(size_t)(px * 256 + r1) * HN + c1 * 16];

    auto stA = [&](int slot, int tt) {
      const unsigned char* s = aSrc + tt * 64;
      unsigned char* d = &sm8[slot * 16384 + tid * 16];
      gload_lds16(s, d);
      gload_lds16(s + (size_t)128 * HN, d + 8192);
    };
    auto stB = [&](int buf, int tt) {
      const unsigned char* s = bSrc + tt * 64;
      unsigned char* d = &sm8[49152 + buf * 16384 + tid * 16];
      gload_lds16(s, d);
      gload_lds16(s + (size_t)128 * HN, d + 8192);
    };

    intx4 acc[8][4];
    #pragma unroll
    for (int m = 0; m < 8; ++m)
      #pragma unroll
      for (int n = 0; n < 4; ++n) acc[m][n] = (intx4){0, 0, 0, 0};

    intx4 af[8], bfr[2];
    auto ldA = [&](int slot) {
      const unsigned char* Ap = &sm8[slot * 16384];
      #pragma unroll
      for (int m = 0; m < 8; ++m)
        af[m] = *reinterpret_cast<const intx4*>(&Ap[(wr128 + m * 16 + lr) * 64 + rdOff]);
    };
    auto ldB = [&](int buf, int nh) {
      const unsigned char* Bp = &sm8[49152 + buf * 16384];
      #pragma unroll
      for (int n = 0; n < 2; ++n)
        bfr[n] = *reinterpret_cast<const intx4*>(
            &Bp[(wc64 + (nh * 2 + n) * 16 + lr) * 64 + rdOff]);
    };
    auto mm = [&](int nh) {
      __builtin_amdgcn_s_setprio(1);
      #pragma unroll
      for (int m = 0; m < 8; ++m)
        #pragma unroll
        for (int n = 0; n < 2; ++n)
          acc[m][nh * 2 + n] = __builtin_amdgcn_mfma_i32_16x16x64_i8(
              af[m], bfr[n], acc[m][nh * 2 + n], 0, 0, 0);
      __builtin_amdgcn_s_setprio(0);
    };

    // prologue: A(0)->slot0, B(0)->buf0, A(1)->slot1 (6 loads); drain 4 oldest
    stA(0, 0); stB(0, 0); stA(1, 1);
    WAITV2; PH_BAR;

    int rs = 0;                                // t % 3
    for (int t = 0; t < 16; ++t) {
      int rb = t & 1, wb = rb ^ 1;
      int ws = rs + 2; if (ws >= 3) ws -= 3;
      int tb = (t + 1 < 16) ? t + 1 : 15;
      int ta = (t + 2 < 16) ? t + 2 : 15;
      // ph0 (nh=0): reads drained by prev tile's WAITV2 + barrier
      ldA(rs); ldB(rb, 0);
      stB(wb, tb);
      PH_BAR; mm(0); PH_BAR;
      // ph1 (nh=1)
      ldB(rb, 1);
      stA(ws, ta);
      WAITV2;                                  // leaves A(t+2); drains A(t+1),B(t+1)
      PH_BAR; mm(1); PH_BAR;
      rs = (rs + 1 == 3) ? 0 : rs + 1;
    }
    WAITV0;                                    // drain tail duplicates

    // epilogue: q[s,col] = sum over 64 a-rows of (acc*INVQ)^2
    int colBase = px * 256 + wc64;
    #pragma unroll
    for (int half = 0; half < 2; ++half) {
      int sOut = py * 4 + wr * 2 + half;
      #pragma unroll
      for (int nf = 0; nf < 4; ++nf) {
        float v = 0.f;
        #pragma unroll
        for (int mf = half * 4; mf < half * 4 + 4; ++mf)
          #pragma unroll
          for (int r = 0; r < 4; ++r) {
            float mi = (float)acc[mf][nf][r] * INVQ;
            v += mi * mi;
          }
        v += __shfl_xor(v, 16, 64);
        v += __shfl_xor(v, 32, 64);
        if (l < 16) q[(size_t)sOut * HN + colBase + nf * 16 + l] = v;
      }
    }
  } else {
    // ---- w section: w[s,j] = sum_k v[s,k] W2[j,k]; 16 s x 128 cols/block ----
    float* redF = reinterpret_cast<float*>(sm8);   // 8 x 16 x 64 = 32 KB
    int wi = bid - 512;
    int m0 = (wi >> 3) * 16, n0 = (wi & 7) * 128;
    int w = tid >> 6, l = tid & 63, lr = l & 15, kg = l >> 4;
    int ks = w >> 1, ch = w & 1;
    floatx4 acc[4];
    #pragma unroll
    for (int nf = 0; nf < 4; ++nf) acc[nf] = (floatx4){0.f, 0.f, 0.f, 0.f};
    int arow = m0 + lr;
    for (int kt = 0; kt < 8; ++kt) {
      int kb = ks * 256 + kt * 32 + kg * 8;
      short8 af = *reinterpret_cast<const short8*>(&vbf[arow * HN + kb]);
      #pragma unroll
      for (int nf = 0; nf < 4; ++nf) {
        short8 bf_ = *reinterpret_cast<const short8*>(
            &W2bf[(size_t)(n0 + ch * 64 + nf * 16 + lr) * HN + kb]);
        acc[nf] = __builtin_amdgcn_mfma_f32_16x16x32_bf16(af, bf_, acc[nf], 0, 0, 0);
      }
    }
    #pragma unroll
    for (int nf = 0; nf < 4; ++nf)
      #pragma unroll
      for (int r = 0; r < 4; ++r)
        redF[w * 1024 + (kg * 4 + r) * 64 + nf * 16 + lr] = acc[nf][r];
    __syncthreads();
    #pragma unroll
    for (int it = 0; it < 4; ++it) {
      int e = it * 512 + tid;                  // 2048 = 16 rows x 128 cols
      int row = e >> 7, col = e & 127;
      int ch2 = col >> 6, cc = col & 63;
      float z = redF[(0 * 2 + ch2) * 1024 + row * 64 + cc]
              + redF[(1 * 2 + ch2) * 1024 + row * 64 + cc]
              + redF[(2 * 2 + ch2) * 1024 + row * 64 + cc]
              + redF[(3 * 2 + ch2) * 1024 + row * 64 + cc];
      wbuf[(size_t)(m0 + row) * HN + n0 + col] = z;
    }
  }
}

// ---------------------------------------------------------------------------
// finale: per sample combine T1, T2, sum g^2, pot+gint
__global__ __launch_bounds__(256) void k_fin(
    const float* __restrict__ wbuf, const float* __restrict__ a1,
    const float* __restrict__ dcoef, const float* __restrict__ q,
    const float* __restrict__ t1f, const float* __restrict__ W1T,
    const float* __restrict__ potgint, float* __restrict__ out) {
  __shared__ float s_lds[HN];
  __shared__ float gl[256];
  __shared__ float red1[4], red2[4];
  int s = blockIdx.x, tid = threadIdx.x;
  float p1 = 0.f, p2 = 0.f;
  #pragma unroll
  for (int cc = 0; cc < 4; ++cc) {
    int j = tid + cc * 256;
    float wv = wbuf[s * HN + j];
    p1 += a1[s * HN + j] * wv;
    p2 += dcoef[s * HN + j] * q[s * HN + j];
    s_lds[j] = t1f[s * HN + j] * wv;
  }
  __syncthreads();
  int part = tid >> 6, a = tid & 63;
  float gp = 0.f;
  for (int jj = part * 256; jj < part * 256 + 256; ++jj)
    gp += s_lds[jj] * W1T[jj * AN + a];
  gl[tid] = gp;
  #pragma unroll
  for (int o = 32; o > 0; o >>= 1) { p1 += __shfl_down(p1, o, 64); p2 += __shfl_down(p2, o, 64); }
  if ((tid & 63) == 0) { red1[tid >> 6] = p1; red2[tid >> 6] = p2; }
  __syncthreads();
  if (tid < 64) {
    float g = gl[tid] + gl[64 + tid] + gl[128 + tid] + gl[192 + tid];
    float sq = g * g;
    #pragma unroll
    for (int o = 32; o > 0; o >>= 1) sq += __shfl_down(sq, o, 64);
    if (tid == 0) {
      float T1 = -2.f * (red1[0] + red1[1] + red1[2] + red1[3]);
      float T2 = red2[0] + red2[1] + red2[2] + red2[3];
      out[s] = -0.5f * (T1 + T2 + sq) + potgint[s];
    }
  }
}

// ---------------------------------------------------------------------------
extern "C" void kernel_launch(void* const* d_in, const int* in_sizes, int n_in,
                              void* d_out, int out_size, void* d_ws, size_t ws_size,
                              hipStream_t stream) {
  const float* x  = (const float*)d_in[0];
  const float* W1 = (const float*)d_in[1];
  const float* b1 = (const float*)d_in[2];
  const float* W2 = (const float*)d_in[3];
  const float* b2 = (const float*)d_in[4];
  const float* W3 = (const float*)d_in[5];
  float* out = (float*)d_out;

  char* ws = (char*)d_ws;
  size_t off = 0;
  auto alloc = [&](size_t bytes) -> void* {
    void* p = ws + off; off += (bytes + 255) & ~(size_t)255; return p;
  };
  unsigned short* W2T  = (unsigned short*)alloc((size_t)HN * HN * 2);
  unsigned short* W2bf = (unsigned short*)alloc((size_t)HN * HN * 2);
  unsigned char*  W2Ti8= (unsigned char*)alloc((size_t)HN * HN);
  float*          W1T  = (float*)alloc((size_t)AN * HN * 4);
  unsigned short* h1bf = (unsigned short*)alloc((size_t)BN * HN * 2);
  float*          t1f  = (float*)alloc((size_t)BN * HN * 4);
  float*          a1   = (float*)alloc((size_t)BN * HN * 4);
  float*          dcoef= (float*)alloc((size_t)BN * HN * 4);
  unsigned short* vbf  = (unsigned short*)alloc((size_t)BN * HN * 2);
  float*          wbuf = (float*)alloc((size_t)BN * HN * 4);
  float*          q    = (float*)alloc((size_t)BN * HN * 4);
  float*          pg   = (float*)alloc((size_t)BN * 4);
  unsigned char*  Pi8  = (unsigned char*)alloc((size_t)BN * AN * HN);  // 33.5 MB

  static bool attrSet = false;
  if (!attrSet) {
    hipFuncSetAttribute((const void*)k_bigw,
                        hipFuncAttributeMaxDynamicSharedMemorySize, 81920);
    attrSet = true;
  }

  k1<<<dim3(BN + 256 + 16), 256, 0, stream>>>(x, W1, b1, W2,
                                              h1bf, t1f, a1, pg,
                                              Pi8, W2T, W2bf, W2Ti8, W1T);
  k_z2<<<dim3(HN / 64, BN / 16), 256, 0, stream>>>(h1bf, W2T, b2, W3, dcoef, vbf);
  k_bigw<<<dim3(512 + 256), 512, 81920, stream>>>(Pi8, W2Ti8, q, vbf, W2bf, wbuf);
  k_fin<<<dim3(BN), 256, 0, stream>>>(wbuf, a1, dcoef, q, t1f, W1T, pg, out);
}

// Round 13
// 145.862 us; speedup vs baseline: 4.2905x; 1.1877x over previous
//
#include <hip/hip_runtime.h>
#include <hip/hip_bf16.h>
#include <stdint.h>

// Problem constants
#define AN 64
#define HN 1024
#define BN 512
#define GAUSS_CONST (-3.989422804014327f)   // V0 / (sqrt(2*pi)*sigma0)
#define INV_2SIG2 2.0f

// int8 quant scales for the big GEMM (headroom-checked: |P|<=~0.53 -> 102,
// |W2|<=~0.16 -> 123; clamp +-127 guards tails; i32 accum exact)
#define SA 192.0f
#define SB 768.0f
#define INVQ (1.0f / (SA * SB))

typedef __attribute__((ext_vector_type(8))) short short8;
typedef __attribute__((ext_vector_type(4))) short short4v;
typedef __attribute__((ext_vector_type(4))) float floatx4;
typedef __attribute__((ext_vector_type(4))) int intx4;

__device__ inline unsigned short f2bf(float f) {
  __hip_bfloat16 h = __float2bfloat16(f);        // RNE
  return *reinterpret_cast<unsigned short*>(&h);
}

__device__ inline unsigned q8(float x, float s) {  // clamp+RNE to int8 byte
  float xc = fminf(fmaxf(x * s, -127.f), 127.f);
  int qi = (int)rintf(xc);
  return (unsigned)(qi & 255);
}

__device__ inline void gload_lds16(const void* g, void* l) {
  __builtin_amdgcn_global_load_lds(
      (const __attribute__((address_space(1))) void*)g,
      (__attribute__((address_space(3))) void*)l, 16, 0, 0);
}

#define PH_BAR  asm volatile("s_barrier" ::: "memory")
#define WAITV2  asm volatile("s_waitcnt vmcnt(2)" ::: "memory")
#define WAITV0  asm volatile("s_waitcnt vmcnt(0)" ::: "memory")

// ---------------------------------------------------------------------------
// k1 (grid-sectioned, all sections depend only on kernel inputs):
//  b < 512       : per-sample layer-1 fwd (h1,t1,a1) + pot/gint  (NO pack --
//                  pack moved to k_z2 launch to cut VGPR/latency pressure)
//  512 <= b<768  : W2 64x64 tile -> W2bf (cast) + W2T (bf16 T) + W2Ti8 (i8 T)
//  768 <= b<784  : W1 64x64 tile -> W1T (f32 T)
__global__ __launch_bounds__(256) void k1(
    const float* __restrict__ x, const float* __restrict__ W1,
    const float* __restrict__ b1, const float* __restrict__ W2,
    unsigned short* __restrict__ h1bf, float* __restrict__ t1f,
    float* __restrict__ a1, float* __restrict__ potgint,
    unsigned short* __restrict__ W2T,
    unsigned short* __restrict__ W2bf, unsigned char* __restrict__ W2Ti8,
    float* __restrict__ W1T) {
  __shared__ float tile[64][65];
  __shared__ float xs[AN];
  __shared__ float red[4];
  int b = blockIdx.x, tid = threadIdx.x;
  if (b < BN) {
    int s = b;
    if (tid < AN) xs[tid] = x[s * AN + tid];
    __syncthreads();
    int j4 = tid * 4;
    floatx4 z4 = *reinterpret_cast<const floatx4*>(&b1[j4]);
    floatx4 cs4 = (floatx4){0.f, 0.f, 0.f, 0.f};
    #pragma unroll 4
    for (int a = 0; a < AN; ++a) {
      floatx4 w = *reinterpret_cast<const floatx4*>(&W1[(size_t)a * HN + j4]);
      float xa = xs[a];
      #pragma unroll
      for (int e = 0; e < 4; ++e) { z4[e] += xa * w[e]; cs4[e] += w[e] * w[e]; }
    }
    floatx4 t4, a4; short4v h4;
    #pragma unroll
    for (int e = 0; e < 4; ++e) {
      float h = tanhf(z4[e]), t = 1.f - h * h;
      h4[e] = (short)f2bf(h);
      t4[e] = t;
      a4[e] = cs4[e] * h * t;
    }
    *reinterpret_cast<short4v*>(&h1bf[(size_t)s * HN + j4]) = h4;
    *reinterpret_cast<floatx4*>(&t1f[(size_t)s * HN + j4]) = t4;
    *reinterpret_cast<floatx4*>(&a1[(size_t)s * HN + j4]) = a4;
    // pot + gint
    float val = 0.f;
    #pragma unroll
    for (int p = 0; p < 16; ++p) {
      int idx = tid + p * 256;
      int i = idx >> 6, jj = idx & 63;
      if (jj > i) { float d = xs[i] - xs[jj]; val += __expf(-INV_2SIG2 * d * d); }
    }
    val *= GAUSS_CONST;
    if (tid < AN) val += 0.5f * xs[tid] * xs[tid];
    #pragma unroll
    for (int o = 32; o > 0; o >>= 1) val += __shfl_down(val, o, 64);
    if ((tid & 63) == 0) red[tid >> 6] = val;
    __syncthreads();
    if (tid == 0) potgint[s] = red[0] + red[1] + red[2] + red[3];
  } else if (b < BN + 256) {
    int t = b - BN;
    int jt = (t >> 4) * 64, kt = (t & 15) * 64;
    #pragma unroll
    for (int it = 0; it < 4; ++it) {
      int e = it * 256 + tid;
      int r = e >> 4, cv = (e & 15) * 4;
      floatx4 v = *reinterpret_cast<const floatx4*>(&W2[(size_t)(jt + r) * HN + kt + cv]);
      tile[r][cv] = v[0]; tile[r][cv + 1] = v[1];
      tile[r][cv + 2] = v[2]; tile[r][cv + 3] = v[3];
      short4v o;
      #pragma unroll
      for (int i = 0; i < 4; ++i) o[i] = (short)f2bf(v[i]);
      *reinterpret_cast<short4v*>(&W2bf[(size_t)(jt + r) * HN + kt + cv]) = o;
    }
    __syncthreads();
    #pragma unroll
    for (int it = 0; it < 4; ++it) {
      int e = it * 256 + tid;
      int r = e >> 4, cv = (e & 15) * 4;     // r: k2-row, cv: j-cols (0..63)
      float v0 = tile[cv][r], v1 = tile[cv + 1][r];
      float v2 = tile[cv + 2][r], v3 = tile[cv + 3][r];
      short4v o;
      o[0] = (short)f2bf(v0); o[1] = (short)f2bf(v1);
      o[2] = (short)f2bf(v2); o[3] = (short)f2bf(v3);
      *reinterpret_cast<short4v*>(&W2T[(size_t)(kt + r) * HN + jt + cv]) = o;
      unsigned p8 = q8(v0, SB) | (q8(v1, SB) << 8)
                  | (q8(v2, SB) << 16) | (q8(v3, SB) << 24);
      *reinterpret_cast<unsigned*>(&W2Ti8[(size_t)(kt + r) * HN + jt + cv]) = p8;
    }
  } else {
    int t = b - (BN + 256);                    // 0..15
    int j0 = t * 64;
    #pragma unroll
    for (int it = 0; it < 4; ++it) {
      int e = it * 256 + tid;
      int r = e >> 4, cv = (e & 15) * 4;
      floatx4 v = *reinterpret_cast<const floatx4*>(&W1[(size_t)r * HN + j0 + cv]);
      tile[r][cv] = v[0]; tile[r][cv + 1] = v[1];
      tile[r][cv + 2] = v[2]; tile[r][cv + 3] = v[3];
    }
    __syncthreads();
    #pragma unroll
    for (int it = 0; it < 4; ++it) {
      int e = it * 256 + tid;
      int r = e >> 4, cv = (e & 15) * 4;
      floatx4 o;
      #pragma unroll
      for (int i = 0; i < 4; ++i) o[i] = tile[cv + i][r];
      *reinterpret_cast<floatx4*>(&W1T[(size_t)(j0 + r) * AN + cv]) = o;
    }
  }
}

// ---------------------------------------------------------------------------
// k_z2p (grid-sectioned; all sections depend only on k1 outputs + inputs):
//  bid < 512   : z2 = h1 @ W2 + b2 -> dcoef, v (bf16)
//  bid >= 512  : P i8 pack (1024 blocks): p=(s, a-half); thread owns 4 j's,
//                t4 loaded once from t1f, 32 independent W1-load->q8->store.
__global__ __launch_bounds__(256) void k_z2p(
    const unsigned short* __restrict__ h1bf, const unsigned short* __restrict__ W2T,
    const float* __restrict__ b2, const float* __restrict__ W3,
    float* __restrict__ dcoef, unsigned short* __restrict__ vbf,
    const float* __restrict__ W1, const float* __restrict__ t1f,
    unsigned char* __restrict__ Pi8) {
  __shared__ float redL[4 * 16 * 64];
  int bid = blockIdx.x, tid = threadIdx.x;
  if (bid < 512) {
    int n0 = (bid & 15) * 64, m0 = (bid >> 4) * 16;
    int w = tid >> 6, l = tid & 63, lr = l & 15, kg = l >> 4;
    floatx4 acc[4];
    #pragma unroll
    for (int nf = 0; nf < 4; ++nf) acc[nf] = (floatx4){0.f, 0.f, 0.f, 0.f};
    int arow = m0 + lr;
    for (int kt = 0; kt < 8; ++kt) {
      int kb = w * 256 + kt * 32 + kg * 8;
      short8 af = *reinterpret_cast<const short8*>(&h1bf[arow * HN + kb]);
      #pragma unroll
      for (int nf = 0; nf < 4; ++nf) {
        short8 bf_ = *reinterpret_cast<const short8*>(&W2T[(n0 + nf * 16 + lr) * HN + kb]);
        acc[nf] = __builtin_amdgcn_mfma_f32_16x16x32_bf16(af, bf_, acc[nf], 0, 0, 0);
      }
    }
    #pragma unroll
    for (int nf = 0; nf < 4; ++nf)
      #pragma unroll
      for (int r = 0; r < 4; ++r)
        redL[w * 1024 + (kg * 4 + r) * 64 + nf * 16 + lr] = acc[nf][r];
    __syncthreads();
    #pragma unroll
    for (int t = 0; t < 4; ++t) {
      int e = tid + t * 256;
      float z = redL[e] + redL[1024 + e] + redL[2048 + e] + redL[3072 + e];
      int row = e >> 6, col = e & 63;
      int s = m0 + row, k2 = n0 + col;
      z += b2[k2];
      float h = tanhf(z), tt = 1.f - h * h, w3 = W3[k2];
      dcoef[s * HN + k2] = -2.f * h * tt * w3;
      vbf[s * HN + k2] = f2bf(tt * w3);
    }
  } else {
    int p = bid - 512;                         // 0..1023
    int s = p >> 1, a0 = (p & 1) * 32;
    int j4 = tid * 4;
    floatx4 t4 = *reinterpret_cast<const floatx4*>(&t1f[(size_t)s * HN + j4]);
    size_t outBase = ((size_t)s * 64 + a0) * HN + j4;
    #pragma unroll 8
    for (int ai = 0; ai < 32; ++ai) {
      int a = a0 + ai;
      floatx4 w = *reinterpret_cast<const floatx4*>(&W1[(size_t)a * HN + j4]);
      unsigned pk = q8(w[0] * t4[0], SA)
                  | (q8(w[1] * t4[1], SA) << 8)
                  | (q8(w[2] * t4[2], SA) << 16)
                  | (q8(w[3] * t4[3], SA) << 24);
      *reinterpret_cast<unsigned*>(&Pi8[outBase + (size_t)ai * HN]) = pk;
    }
  }
}

// ---------------------------------------------------------------------------
// k_bigw (512-thread blocks, 80 KB dyn LDS):
//  bid < 512 : BIG i8 GEMM, 2 phases/tile x 16 MFMA (K=64 per instr).
//  bid >= 512: w = v @ W2^T section (256 blocks, 8-wave split-K).
//
// BIG: q[s,k] = sum_a M[a,k]^2, M = P[s]@W2 (i8 xSA/xSB, epilogue xINVQ^2).
// BM=256 x BN=256, BK=64. LDS: A ring 3x16KB + B dbuf 2x16KB = 80KB.
// Operands LINEAR: row = 64 consecutive k-bytes; lane (lr,kg) reads its
// 16x16x64-i8 fragment (k = kg*16 + i) as ONE ds_read_b128 at
// row*64 + ((kg ^ ((lr>>1)&3))<<4)  (16B-chunk XOR swizzle, 2 lanes/bank).
// Staging (m104: dest = wave-uniform + lane*16): load1 dest = base+tid*16
// (row tid>>2, phys chunk tid&3), load2 dest = +8192 (row +128). Source
// chunk c1 = (tid&3) ^ ((tid>>3)&3) (same involution as read side).
// Ledger: stB(t+1)@ph0, stA(t+2)@ph1, ONE WAITV2/tile at ph1.
__global__ __launch_bounds__(512, 2) void k_bigw(
    const unsigned char* __restrict__ Pi8,    // [32768][HN] i8, linear
    const unsigned char* __restrict__ W2Ti8,  // [1024][1024] i8, linear
    float* __restrict__ q,
    const unsigned short* __restrict__ vbf, const unsigned short* __restrict__ W2bf,
    float* __restrict__ wbuf) {
  extern __shared__ unsigned char sm8[];
  int bid = blockIdx.x;
  int tid = threadIdx.x;

  if (bid < 512) {
    // ---- BIG section ----
    int xcd = bid & 7, local = bid >> 3;
    int px = local & 3;                        // col panel (fastest, same XCD)
    int py = xcd * 16 + (local >> 2);          // XCD-exclusive A range

    int wid = tid >> 6, l = tid & 63;
    int lr = l & 15, kg = l >> 4;
    int wr = wid >> 2, wc = wid & 3;
    int wr128 = wr * 128, wc64 = wc * 64;
    int rdOff = ((kg ^ ((lr >> 1) & 3)) << 4); // b128 chunk (swizzled)

    int r1 = tid >> 2;
    int c1 = (tid & 3) ^ ((tid >> 3) & 3);
    const unsigned char* aSrc = &Pi8[(size_t)(py * 256 + r1) * HN + c1 * 16];
    const unsigned char* bSrc = &W2Ti8[(size_t)(px * 256 + r1) * HN + c1 * 16];

    auto stA = [&](int slot, int tt) {
      const unsigned char* s = aSrc + tt * 64;
      unsigned char* d = &sm8[slot * 16384 + tid * 16];
      gload_lds16(s, d);
      gload_lds16(s + (size_t)128 * HN, d + 8192);
    };
    auto stB = [&](int buf, int tt) {
      const unsigned char* s = bSrc + tt * 64;
      unsigned char* d = &sm8[49152 + buf * 16384 + tid * 16];
      gload_lds16(s, d);
      gload_lds16(s + (size_t)128 * HN, d + 8192);
    };

    intx4 acc[8][4];
    #pragma unroll
    for (int m = 0; m < 8; ++m)
      #pragma unroll
      for (int n = 0; n < 4; ++n) acc[m][n] = (intx4){0, 0, 0, 0};

    intx4 af[8], bfr[2];
    auto ldA = [&](int slot) {
      const unsigned char* Ap = &sm8[slot * 16384];
      #pragma unroll
      for (int m = 0; m < 8; ++m)
        af[m] = *reinterpret_cast<const intx4*>(&Ap[(wr128 + m * 16 + lr) * 64 + rdOff]);
    };
    auto ldB = [&](int buf, int nh) {
      const unsigned char* Bp = &sm8[49152 + buf * 16384];
      #pragma unroll
      for (int n = 0; n < 2; ++n)
        bfr[n] = *reinterpret_cast<const intx4*>(
            &Bp[(wc64 + (nh * 2 + n) * 16 + lr) * 64 + rdOff]);
    };
    auto mm = [&](int nh) {
      __builtin_amdgcn_s_setprio(1);
      #pragma unroll
      for (int m = 0; m < 8; ++m)
        #pragma unroll
        for (int n = 0; n < 2; ++n)
          acc[m][nh * 2 + n] = __builtin_amdgcn_mfma_i32_16x16x64_i8(
              af[m], bfr[n], acc[m][nh * 2 + n], 0, 0, 0);
      __builtin_amdgcn_s_setprio(0);
    };

    // prologue: A(0)->slot0, B(0)->buf0, A(1)->slot1 (6 loads); drain 4 oldest
    stA(0, 0); stB(0, 0); stA(1, 1);
    WAITV2; PH_BAR;

    int rs = 0;                                // t % 3
    for (int t = 0; t < 16; ++t) {
      int rb = t & 1, wb = rb ^ 1;
      int ws = rs + 2; if (ws >= 3) ws -= 3;
      int tb = (t + 1 < 16) ? t + 1 : 15;
      int ta = (t + 2 < 16) ? t + 2 : 15;
      // ph0 (nh=0): reads drained by prev tile's WAITV2 + barrier
      ldA(rs); ldB(rb, 0);
      stB(wb, tb);
      PH_BAR; mm(0); PH_BAR;
      // ph1 (nh=1)
      ldB(rb, 1);
      stA(ws, ta);
      WAITV2;                                  // leaves A(t+2); drains A(t+1),B(t+1)
      PH_BAR; mm(1); PH_BAR;
      rs = (rs + 1 == 3) ? 0 : rs + 1;
    }
    WAITV0;                                    // drain tail duplicates

    // epilogue: q[s,col] = sum over 64 a-rows of (acc*INVQ)^2
    int colBase = px * 256 + wc64;
    #pragma unroll
    for (int half = 0; half < 2; ++half) {
      int sOut = py * 4 + wr * 2 + half;
      #pragma unroll
      for (int nf = 0; nf < 4; ++nf) {
        float v = 0.f;
        #pragma unroll
        for (int mf = half * 4; mf < half * 4 + 4; ++mf)
          #pragma unroll
          for (int r = 0; r < 4; ++r) {
            float mi = (float)acc[mf][nf][r] * INVQ;
            v += mi * mi;
          }
        v += __shfl_xor(v, 16, 64);
        v += __shfl_xor(v, 32, 64);
        if (l < 16) q[(size_t)sOut * HN + colBase + nf * 16 + l] = v;
      }
    }
  } else {
    // ---- w section: w[s,j] = sum_k v[s,k] W2[j,k]; 16 s x 128 cols/block ----
    float* redF = reinterpret_cast<float*>(sm8);   // 8 x 16 x 64 = 32 KB
    int wi = bid - 512;
    int m0 = (wi >> 3) * 16, n0 = (wi & 7) * 128;
    int w = tid >> 6, l = tid & 63, lr = l & 15, kg = l >> 4;
    int ks = w >> 1, ch = w & 1;
    floatx4 acc[4];
    #pragma unroll
    for (int nf = 0; nf < 4; ++nf) acc[nf] = (floatx4){0.f, 0.f, 0.f, 0.f};
    int arow = m0 + lr;
    for (int kt = 0; kt < 8; ++kt) {
      int kb = ks * 256 + kt * 32 + kg * 8;
      short8 af = *reinterpret_cast<const short8*>(&vbf[arow * HN + kb]);
      #pragma unroll
      for (int nf = 0; nf < 4; ++nf) {
        short8 bf_ = *reinterpret_cast<const short8*>(
            &W2bf[(size_t)(n0 + ch * 64 + nf * 16 + lr) * HN + kb]);
        acc[nf] = __builtin_amdgcn_mfma_f32_16x16x32_bf16(af, bf_, acc[nf], 0, 0, 0);
      }
    }
    #pragma unroll
    for (int nf = 0; nf < 4; ++nf)
      #pragma unroll
      for (int r = 0; r < 4; ++r)
        redF[w * 1024 + (kg * 4 + r) * 64 + nf * 16 + lr] = acc[nf][r];
    __syncthreads();
    #pragma unroll
    for (int it = 0; it < 4; ++it) {
      int e = it * 512 + tid;                  // 2048 = 16 rows x 128 cols
      int row = e >> 7, col = e & 127;
      int ch2 = col >> 6, cc = col & 63;
      float z = redF[(0 * 2 + ch2) * 1024 + row * 64 + cc]
              + redF[(1 * 2 + ch2) * 1024 + row * 64 + cc]
              + redF[(2 * 2 + ch2) * 1024 + row * 64 + cc]
              + redF[(3 * 2 + ch2) * 1024 + row * 64 + cc];
      wbuf[(size_t)(m0 + row) * HN + n0 + col] = z;
    }
  }
}

// ---------------------------------------------------------------------------
// finale: per sample combine T1, T2, sum g^2, pot+gint
__global__ __launch_bounds__(256) void k_fin(
    const float* __restrict__ wbuf, const float* __restrict__ a1,
    const float* __restrict__ dcoef, const float* __restrict__ q,
    const float* __restrict__ t1f, const float* __restrict__ W1T,
    const float* __restrict__ potgint, float* __restrict__ out) {
  __shared__ float s_lds[HN];
  __shared__ float gl[256];
  __shared__ float red1[4], red2[4];
  int s = blockIdx.x, tid = threadIdx.x;
  float p1 = 0.f, p2 = 0.f;
  #pragma unroll
  for (int cc = 0; cc < 4; ++cc) {
    int j = tid + cc * 256;
    float wv = wbuf[s * HN + j];
    p1 += a1[s * HN + j] * wv;
    p2 += dcoef[s * HN + j] * q[s * HN + j];
    s_lds[j] = t1f[s * HN + j] * wv;
  }
  __syncthreads();
  int part = tid >> 6, a = tid & 63;
  float gp = 0.f;
  for (int jj = part * 256; jj < part * 256 + 256; ++jj)
    gp += s_lds[jj] * W1T[jj * AN + a];
  gl[tid] = gp;
  #pragma unroll
  for (int o = 32; o > 0; o >>= 1) { p1 += __shfl_down(p1, o, 64); p2 += __shfl_down(p2, o, 64); }
  if ((tid & 63) == 0) { red1[tid >> 6] = p1; red2[tid >> 6] = p2; }
  __syncthreads();
  if (tid < 64) {
    float g = gl[tid] + gl[64 + tid] + gl[128 + tid] + gl[192 + tid];
    float sq = g * g;
    #pragma unroll
    for (int o = 32; o > 0; o >>= 1) sq += __shfl_down(sq, o, 64);
    if (tid == 0) {
      float T1 = -2.f * (red1[0] + red1[1] + red1[2] + red1[3]);
      float T2 = red2[0] + red2[1] + red2[2] + red2[3];
      out[s] = -0.5f * (T1 + T2 + sq) + potgint[s];
    }
  }
}

// ---------------------------------------------------------------------------
extern "C" void kernel_launch(void* const* d_in, const int* in_sizes, int n_in,
                              void* d_out, int out_size, void* d_ws, size_t ws_size,
                              hipStream_t stream) {
  const float* x  = (const float*)d_in[0];
  const float* W1 = (const float*)d_in[1];
  const float* b1 = (const float*)d_in[2];
  const float* W2 = (const float*)d_in[3];
  const float* b2 = (const float*)d_in[4];
  const float* W3 = (const float*)d_in[5];
  float* out = (float*)d_out;

  char* ws = (char*)d_ws;
  size_t off = 0;
  auto alloc = [&](size_t bytes) -> void* {
    void* p = ws + off; off += (bytes + 255) & ~(size_t)255; return p;
  };
  unsigned short* W2T  = (unsigned short*)alloc((size_t)HN * HN * 2);
  unsigned short* W2bf = (unsigned short*)alloc((size_t)HN * HN * 2);
  unsigned char*  W2Ti8= (unsigned char*)alloc((size_t)HN * HN);
  float*          W1T  = (float*)alloc((size_t)AN * HN * 4);
  unsigned short* h1bf = (unsigned short*)alloc((size_t)BN * HN * 2);
  float*          t1f  = (float*)alloc((size_t)BN * HN * 4);
  float*          a1   = (float*)alloc((size_t)BN * HN * 4);
  float*          dcoef= (float*)alloc((size_t)BN * HN * 4);
  unsigned short* vbf  = (unsigned short*)alloc((size_t)BN * HN * 2);
  float*          wbuf = (float*)alloc((size_t)BN * HN * 4);
  float*          q    = (float*)alloc((size_t)BN * HN * 4);
  float*          pg   = (float*)alloc((size_t)BN * 4);
  unsigned char*  Pi8  = (unsigned char*)alloc((size_t)BN * AN * HN);  // 33.5 MB

  static bool attrSet = false;
  if (!attrSet) {
    hipFuncSetAttribute((const void*)k_bigw,
                        hipFuncAttributeMaxDynamicSharedMemorySize, 81920);
    attrSet = true;
  }

  k1<<<dim3(BN + 256 + 16), 256, 0, stream>>>(x, W1, b1, W2,
                                              h1bf, t1f, a1, pg,
                                              W2T, W2bf, W2Ti8, W1T);
  k_z2p<<<dim3(512 + 1024), 256, 0, stream>>>(h1bf, W2T, b2, W3, dcoef, vbf,
                                              W1, t1f, Pi8);
  k_bigw<<<dim3(512 + 256), 512, 81920, stream>>>(Pi8, W2Ti8, q, vbf, W2bf, wbuf);
  k_fin<<<dim3(BN), 256, 0, stream>>>(wbuf, a1, dcoef, q, t1f, W1T, pg, out);
}